// Round 3
// baseline (715.847 us; speedup 1.0000x reference)
//
#include <hip/hip_runtime.h>
#include <hip/hip_bf16.h>
#include <math.h>

// Problem constants
#define BB 8
#define LL 1024
#define DD 1024
#define FF 4096
#define NHH 8
#define HSS 128
#define SCALE 0.08838834764831845f  // 1/sqrt(128)
#define TRI(qi, kt) ((qi) * ((qi) + 1) / 2 + (kt))

typedef __bf16 bf16;
typedef __bf16 bf16x8 __attribute__((ext_vector_type(8)));
typedef float f32x4 __attribute__((ext_vector_type(4)));
typedef _Float16 f16;
typedef _Float16 f16x4 __attribute__((ext_vector_type(4)));

__device__ inline void async_copy16(const void* g, void* l) {
  __builtin_amdgcn_global_load_lds(
      (const __attribute__((address_space(1))) unsigned int*)g,
      (__attribute__((address_space(3))) unsigned int*)l, 16, 0, 0);
}

// ---------------------------------------------------------------------------
// Transpose + cast: W [K][N] fp32 -> Wt [N][K] bf16
// ---------------------------------------------------------------------------
__global__ __launch_bounds__(256)
void transpose_cast_kernel(const float* __restrict__ W, bf16* __restrict__ Wt,
                           int K, int N) {
  __shared__ float tile[32][33];
  int n0 = blockIdx.x * 32, k0 = blockIdx.y * 32;
  int tx = threadIdx.x, ty = threadIdx.y;
#pragma unroll
  for (int i = 0; i < 32; i += 8)
    tile[ty + i][tx] = W[(size_t)(k0 + ty + i) * N + n0 + tx];
  __syncthreads();
#pragma unroll
  for (int i = 0; i < 32; i += 8)
    Wt[(size_t)(n0 + ty + i) * K + k0 + tx] = (bf16)tile[tx][ty + i];
}

__global__ __launch_bounds__(256)
void cast_bf16_kernel(const float* __restrict__ src, bf16* __restrict__ dst, int n) {
  int i = blockIdx.x * blockDim.x + threadIdx.x;
  if (i < n) dst[i] = (bf16)src[i];
}

// ---------------------------------------------------------------------------
// LayerNorm: x [8192][1024] fp32 -> out bf16
// ---------------------------------------------------------------------------
__global__ __launch_bounds__(256)
void ln_kernel(const float* __restrict__ x, const float* __restrict__ g,
               const float* __restrict__ bta, bf16* __restrict__ out) {
  int row = blockIdx.x;
  int tid = threadIdx.x;
  const float4 v = ((const float4*)(x + (size_t)row * DD))[tid];
  float s = v.x + v.y + v.z + v.w;
  float s2 = v.x * v.x + v.y * v.y + v.z * v.z + v.w * v.w;
#pragma unroll
  for (int o = 32; o > 0; o >>= 1) {
    s += __shfl_down(s, o);
    s2 += __shfl_down(s2, o);
  }
  __shared__ float a1[4], a2[4];
  int wave = tid >> 6;
  if ((tid & 63) == 0) { a1[wave] = s; a2[wave] = s2; }
  __syncthreads();
  s = a1[0] + a1[1] + a1[2] + a1[3];
  s2 = a2[0] + a2[1] + a2[2] + a2[3];
  float mu = s * (1.0f / DD);
  float rstd = rsqrtf(s2 * (1.0f / DD) - mu * mu + 1e-5f);
  float4 gv = ((const float4*)g)[tid];
  float4 bv = ((const float4*)bta)[tid];
  bf16* o4 = out + (size_t)row * DD + tid * 4;
  o4[0] = (bf16)((v.x - mu) * rstd * gv.x + bv.x);
  o4[1] = (bf16)((v.y - mu) * rstd * gv.y + bv.y);
  o4[2] = (bf16)((v.z - mu) * rstd * gv.z + bv.z);
  o4[3] = (bf16)((v.w - mu) * rstd * gv.w + bv.w);
}

// ---------------------------------------------------------------------------
// GEMM v3 (m97-exact structure): C[M][N] = A[M][K](bf16) * Bt[N][K](bf16)^T
// 128x128 tile, BK=64, SINGLE-buffered 32KB LDS, two barriers per K-step,
// global_load_lds width 16. Latency hiding comes from 3-5 resident blocks/CU
// (implicit wave-level overlap, m114) — NOT explicit dbuf (m132 regression).
// XOR chunk swizzle (chunk ^ row&7) on the GLOBAL SOURCE (linear LDS dest
// required by global_load_lds) re-applied on the ds_read side -> conflict-free
// b128 fragment reads. No XCD swizzle (measured: doubled FETCH_SIZE here).
// EPI 0: -> bf16   EPI 1: gelu -> bf16   EPI 2: + res(fp32) -> fp32
// ---------------------------------------------------------------------------
template <int EPI>
__global__ __launch_bounds__(256)
void gemm_kernel(const bf16* __restrict__ A, const bf16* __restrict__ Bt,
                 const float* __restrict__ bias, const float* __restrict__ res,
                 void* __restrict__ Cout, int M, int N, int K) {
  __shared__ bf16 Als[128 * 64];
  __shared__ bf16 Bls[128 * 64];
  int tid = threadIdx.x;
  int wave = tid >> 6, lane = tid & 63;
  int l15 = lane & 15, quad = lane >> 4;

  int m0 = blockIdx.y * 128, n0 = blockIdx.x * 128;
  int wm = (wave >> 1) * 64, wn = (wave & 1) * 64;
  f32x4 acc[4][4] = {};

  // Precompute per-thread staging addresses (k0-invariant).
  // chunk id u = i*256+tid; row = u>>3, c = u&7; source chunk g = c ^ (row&7)
  const bf16* asrc[4];
  const bf16* bsrc[4];
  int ldso[4];
#pragma unroll
  for (int i = 0; i < 4; i++) {
    int u = i * 256 + tid;
    int row = u >> 3, c = u & 7;
    int g = c ^ (row & 7);
    asrc[i] = A + (size_t)(m0 + row) * K + g * 8;
    bsrc[i] = Bt + (size_t)(n0 + row) * K + g * 8;
    ldso[i] = u * 8;
  }

  for (int k0 = 0; k0 < K; k0 += 64) {
    __syncthreads();  // previous iteration's readers done before overwrite
#pragma unroll
    for (int i = 0; i < 4; i++) {
      async_copy16(asrc[i] + k0, &Als[ldso[i]]);
      async_copy16(bsrc[i] + k0, &Bls[ldso[i]]);
    }
    __syncthreads();  // compiler drains vmcnt(0) here: DMA complete

    bf16x8 af[2][4], bfr[2][4];
#pragma unroll
    for (int kk = 0; kk < 2; kk++) {
#pragma unroll
      for (int mt = 0; mt < 4; mt++) {
        int ra = wm + mt * 16 + l15;
        af[kk][mt] = *(const bf16x8*)&Als[ra * 64 + (((kk * 4 + quad) ^ (ra & 7)) << 3)];
        int rb = wn + mt * 16 + l15;
        bfr[kk][mt] = *(const bf16x8*)&Bls[rb * 64 + (((kk * 4 + quad) ^ (rb & 7)) << 3)];
      }
    }
#pragma unroll
    for (int kk = 0; kk < 2; kk++)
#pragma unroll
      for (int mt = 0; mt < 4; mt++)
#pragma unroll
        for (int nt = 0; nt < 4; nt++)
          acc[mt][nt] = __builtin_amdgcn_mfma_f32_16x16x32_bf16(af[kk][mt], bfr[kk][nt],
                                                                acc[mt][nt], 0, 0, 0);
  }

#pragma unroll
  for (int mt = 0; mt < 4; mt++) {
#pragma unroll
    for (int nt = 0; nt < 4; nt++) {
      int col = n0 + wn + nt * 16 + l15;
      float bv = bias[col];
#pragma unroll
      for (int r = 0; r < 4; r++) {
        int row = m0 + wm + mt * 16 + quad * 4 + r;
        float v = acc[mt][nt][r] + bv;
        if (EPI == 1) v = 0.5f * v * (1.0f + erff(v * 0.7071067811865475f));
        if (EPI == 2) {
          v += res[(size_t)row * N + col];
          ((float*)Cout)[(size_t)row * N + col] = v;
        } else {
          ((bf16*)Cout)[(size_t)row * N + col] = (bf16)v;
        }
      }
    }
  }
}

// ---------------------------------------------------------------------------
// pack_kv: per (b,h,kt) repack K into [kk][chunk^swizzle] and V transposed
// into [d][chunk^swizzle], 16B chunks, so flash can DMA-stage with
// global_load_lds and read fragments conflict-free.
// ---------------------------------------------------------------------------
__global__ __launch_bounds__(256)
void pack_kv_kernel(const bf16* __restrict__ qkv, bf16* __restrict__ Kpack,
                    bf16* __restrict__ Vpack) {
  __shared__ bf16 Vst[64][132];  // raw V tile [kk][d], padded
  int kt = blockIdx.x, h = blockIdx.y, b = blockIdx.z;
  int tid = threadIdx.x;
  const size_t rs = 3 * DD;
  const bf16* kb = qkv + (size_t)b * LL * rs + (size_t)(kt * 64) * rs + DD + h * HSS;
  const bf16* vb = kb + DD;
  bf16* kp = Kpack + ((size_t)(b * NHH + h) * 16 + kt) * (64 * 128);
  bf16* vp = Vpack + ((size_t)(b * NHH + h) * 16 + kt) * (128 * 64);
#pragma unroll
  for (int i = 0; i < 4; i++) {
    int u = i * 256 + tid;
    int kk = u >> 4, c = u & 15;
    // K: element (kk,d): chunk c=d>>3 stored at (c ^ (kk&15))
    bf16x8 kv = *(const bf16x8*)(kb + (size_t)kk * rs + c * 8);
    *(bf16x8*)(kp + kk * 128 + ((c ^ kk) & 15) * 8) = kv;
    // V raw stage for transpose
    *(bf16x8*)&Vst[kk][c * 8] = *(const bf16x8*)(vb + (size_t)kk * rs + c * 8);
  }
  __syncthreads();
#pragma unroll
  for (int i = 0; i < 4; i++) {
    int u = i * 256 + tid;
    int d = u >> 3, c = u & 7;  // V^T row d, kk-chunk c (kk = c*8+j)
    bf16x8 t;
#pragma unroll
    for (int j = 0; j < 8; j++) t[j] = Vst[c * 8 + j][d];
    *(bf16x8*)(vp + d * 64 + ((c ^ (d & 7))) * 8) = t;
  }
}

// ---------------------------------------------------------------------------
// Flash attention v7: relband FUSED. Per k-tile, the wave computes its own
// Srel fragments in-register: R = Q@Er^T via MFMA (Er fragments loaded from
// global Erb, 256KB L2-resident, issued BEFORE the K/V prefetch DMA so their
// vmcnt wait doesn't drain the prefetch), then the skew-diagonal gather
// Srel[q][k] = R[q][1023-q+k] via __shfl, added to QK^T scores in f32.
// Eliminates the 117us relband kernel + 71MB band materialization + re-read.
// Balanced pairing (block does q-tiles x and 15-x -> 17 k-tiles per block,
// grid 512 uniform blocks) + LDS double-buffered K/V DMA.
// ---------------------------------------------------------------------------
__global__ __launch_bounds__(256)
void flash_kernel(const bf16* __restrict__ qkv, const bf16* __restrict__ Kpack,
                  const bf16* __restrict__ Vpack, const bf16* __restrict__ Erb,
                  bf16* __restrict__ y) {
  __shared__ bf16 Kls[2][64 * 128];  // [kk][chunk^kk swizzle], double-buffered
  __shared__ bf16 Vls[2][128 * 64];  // [d][chunk^d swizzle], double-buffered
  __shared__ bf16 Pls[4][16][72];

  int tid = threadIdx.x, wave = tid >> 6, lane = tid & 63;
  int l15 = lane & 15, quad = lane >> 4;
  int h = blockIdx.y, b = blockIdx.z;

  const size_t rs = 3 * DD;
  const bf16* qbase = qkv + (size_t)b * LL * rs + h * HSS;
  const bf16* kp = Kpack + (size_t)(b * NHH + h) * 16 * (64 * 128);
  const bf16* vp = Vpack + (size_t)(b * NHH + h) * 16 * (128 * 64);

  int buf = 0;  // global tile parity across both phases
#pragma unroll 1
  for (int ph = 0; ph < 2; ph++) {
    int qb = ph ? 15 - blockIdx.x : blockIdx.x;
    int qw0 = qb * 64 + wave * 16;
    int nkt = qb + 1;

    bf16x8 qf[4];
#pragma unroll
    for (int st = 0; st < 4; st++)
      qf[st] = *(const bf16x8*)(qbase + (size_t)(qw0 + l15) * rs + st * 32 + quad * 8);

    // prologue DMA: tile 0 of this phase into current buffer
    {
      const bf16* ks = kp;
      const bf16* vs = vp;
#pragma unroll
      for (int i = 0; i < 4; i++) {
        int off = (wave * 4 + i) * 512 + lane * 8;
        async_copy16(ks + off, &Kls[buf][off]);
        async_copy16(vs + off, &Vls[buf][off]);
      }
    }

    f32x4 o[8] = {};
    float mrow[4] = {-INFINITY, -INFINITY, -INFINITY, -INFINITY};
    float lrow[4] = {0.f, 0.f, 0.f, 0.f};

#pragma unroll 1
    for (int kt = 0; kt < nkt; kt++) {
      int k0 = kt * 64;
      int kmax_off = qw0 + 15 - k0;  // wave-uniform
      int m_base = 1008 - qw0 + k0;
      int ntR = (kmax_off >> 4) + 1;
      if (ntR > 4) ntR = 4;
      __syncthreads();  // drains DMA for tile kt; prev-tile readers done

      // (1) Er fragment loads FIRST (in-order vmcnt retire: waiting on these
      // does not drain the prefetch DMA issued below)
      bf16x8 ef[5][4];
#pragma unroll
      for (int n = 0; n < 5; n++) {
        if (n <= ntR) {
          int mr = m_base + n * 16 + l15;
          mr = mr < 0 ? 0 : (mr > 1023 ? 1023 : mr);
#pragma unroll
          for (int st = 0; st < 4; st++)
            ef[n][st] = *(const bf16x8*)(Erb + (size_t)mr * HSS + st * 32 + quad * 8);
        }
      }

      // (2) prefetch DMA: tile kt+1 into alternate buffer
      if (kt + 1 < nkt) {
        const bf16* ks = kp + (size_t)(kt + 1) * (64 * 128);
        const bf16* vs = vp + (size_t)(kt + 1) * (128 * 64);
#pragma unroll
        for (int i = 0; i < 4; i++) {
          int off = (wave * 4 + i) * 512 + lane * 8;
          async_copy16(ks + off, &Kls[buf ^ 1][off]);
          async_copy16(vs + off, &Vls[buf ^ 1][off]);
        }
      }

      // (3) R = Q @ Er^T tiles in C-layout: rr[n][rg] = R[qw0+quad*4+rg][m_base+n*16+l15]
      f32x4 rr[5] = {};
#pragma unroll
      for (int n = 0; n < 5; n++) {
        if (n <= ntR) {
#pragma unroll
          for (int st = 0; st < 4; st++)
            rr[n] = __builtin_amdgcn_mfma_f32_16x16x32_bf16(qf[st], ef[n][st], rr[n], 0, 0, 0);
        }
      }

      // (4) S = Q K^T
      f32x4 sa[4] = {};
#pragma unroll
      for (int nt = 0; nt < 4; nt++) {
        if (nt * 16 <= kmax_off) {
          int kk = nt * 16 + l15;
#pragma unroll
          for (int st = 0; st < 4; st++) {
            bf16x8 kf = *(const bf16x8*)&Kls[buf][kk * 128 + (((st * 4 + quad) ^ l15) & 15) * 8];
            sa[nt] = __builtin_amdgcn_mfma_f32_16x16x32_bf16(qf[st], kf, sa[nt], 0, 0, 0);
          }
        }
      }

      // (5) skew gather + combine + mask + row max
      // Srel[q][k] = R[q][1023-q+k]; for fragment elem (rg, nt, l15):
      // m = m_base + nt*16 + tt, tt = 15-qloc+l15 in [0,30]
      float pmx[4] = {-INFINITY, -INFINITY, -INFINITY, -INFINITY};
#pragma unroll
      for (int rg = 0; rg < 4; rg++) {
        int qloc = quad * 4 + rg;
        int qg = qw0 + qloc;
        int tt = 15 - qloc + l15;           // 0..30
        int src = (lane & 48) | (tt & 15);  // same quad-row, rotated col
        float shv[5];
#pragma unroll
        for (int n = 0; n < 5; n++)
          shv[n] = (n <= ntR) ? __shfl(rr[n][rg], src) : 0.f;
#pragma unroll
        for (int nt = 0; nt < 4; nt++) {
          if (nt * 16 <= kmax_off) {
            int kg = k0 + nt * 16 + l15;
            float srel = (tt & 16) ? shv[nt + 1] : shv[nt];
            float v = (sa[nt][rg] + srel) * SCALE;
            v = (kg <= qg) ? v : -INFINITY;
            sa[nt][rg] = v;
            pmx[rg] = fmaxf(pmx[rg], v);
          } else {
            sa[nt][rg] = -INFINITY;
          }
        }
      }

      // online softmax (per 16-lane row group)
#pragma unroll
      for (int rg = 0; rg < 4; rg++) {
        float v = pmx[rg];
        v = fmaxf(v, __shfl_xor(v, 1));
        v = fmaxf(v, __shfl_xor(v, 2));
        v = fmaxf(v, __shfl_xor(v, 4));
        v = fmaxf(v, __shfl_xor(v, 8));
        float mnew = fmaxf(mrow[rg], v);
        float alpha = __expf(mrow[rg] - mnew);
        mrow[rg] = mnew;
        lrow[rg] *= alpha;
#pragma unroll
        for (int nt = 0; nt < 8; nt++) o[nt][rg] *= alpha;
        pmx[rg] = mnew;
      }
      float ls[4] = {0.f, 0.f, 0.f, 0.f};
#pragma unroll
      for (int nt = 0; nt < 4; nt++)
#pragma unroll
        for (int rg = 0; rg < 4; rg++) {
          float p = __expf(sa[nt][rg] - pmx[rg]);
          ls[rg] += p;
          Pls[wave][quad * 4 + rg][nt * 16 + l15] = (bf16)p;
        }
#pragma unroll
      for (int rg = 0; rg < 4; rg++) {
        float v = ls[rg];
        v += __shfl_xor(v, 1);
        v += __shfl_xor(v, 2);
        v += __shfl_xor(v, 4);
        v += __shfl_xor(v, 8);
        lrow[rg] += v;
      }
      // Pls is per-wave: same-wave DS ordering suffices, no barrier

      // O += P @ V
      bf16x8 pf[2];
#pragma unroll
      for (int s2 = 0; s2 < 2; s2++)
        pf[s2] = *(const bf16x8*)&Pls[wave][l15][s2 * 32 + quad * 8];
#pragma unroll
      for (int nt = 0; nt < 8; nt++) {
        int d = nt * 16 + l15;
#pragma unroll
        for (int s2 = 0; s2 < 2; s2++) {
          if (s2 * 32 <= kmax_off) {
            bf16x8 vf = *(const bf16x8*)&Vls[buf][d * 64 + (((s2 * 4 + quad) ^ (l15 & 7)) & 7) * 8];
            o[nt] = __builtin_amdgcn_mfma_f32_16x16x32_bf16(pf[s2], vf, o[nt], 0, 0, 0);
          }
        }
      }
      buf ^= 1;
    }

    // finalize phase: O / l -> y[b, q, h*128 + d] bf16
#pragma unroll
    for (int rg = 0; rg < 4; rg++) {
      float inv = 1.0f / lrow[rg];
      int qg = qw0 + quad * 4 + rg;
      bf16* yr = y + ((size_t)b * LL + qg) * DD + h * HSS;
#pragma unroll
      for (int nt = 0; nt < 8; nt++) yr[nt * 16 + l15] = (bf16)(o[nt][rg] * inv);
    }
  }
}

// ---------------------------------------------------------------------------
extern "C" void kernel_launch(void* const* d_in, const int* in_sizes, int n_in,
                              void* d_out, int out_size, void* d_ws, size_t ws_size,
                              hipStream_t stream) {
  const float* x = (const float*)d_in[0];
  const float* W_qkv = (const float*)d_in[1];
  const float* b_qkv = (const float*)d_in[2];
  const float* W_o = (const float*)d_in[3];
  const float* b_o = (const float*)d_in[4];
  const float* Er = (const float*)d_in[5];
  const float* ln1_g = (const float*)d_in[6];
  const float* ln1_b = (const float*)d_in[7];
  const float* ln2_g = (const float*)d_in[8];
  const float* ln2_b = (const float*)d_in[9];
  const float* W_fc = (const float*)d_in[10];
  const float* b_fc = (const float*)d_in[11];
  const float* W_proj = (const float*)d_in[12];
  const float* b_proj = (const float*)d_in[13];
  float* out = (float*)d_out;

  char* p = (char*)d_ws;
  auto alloc = [&](size_t bytes) {
    char* r = p;
    p += (bytes + 255) & ~(size_t)255;
    return r;
  };
  bf16* Wt_qkv = (bf16*)alloc((size_t)3072 * 1024 * 2);
  bf16* Wt_o   = (bf16*)alloc((size_t)1024 * 1024 * 2);
  bf16* Wt_fc  = (bf16*)alloc((size_t)4096 * 1024 * 2);
  bf16* Wt_pr  = (bf16*)alloc((size_t)1024 * 4096 * 2);
  bf16* Erb    = (bf16*)alloc((size_t)1024 * 128 * 2);
  bf16* xn     = (bf16*)alloc((size_t)8192 * 1024 * 2);
  bf16* qkvb   = (bf16*)alloc((size_t)8192 * 3072 * 2);  // + yb = hb region
  bf16* yb     = (bf16*)alloc((size_t)8192 * 1024 * 2);  // must follow qkvb
  bf16* Kpack  = (bf16*)alloc((size_t)64 * 16 * 64 * 128 * 2);
  bf16* Vpack  = (bf16*)alloc((size_t)64 * 16 * 128 * 64 * 2);
  float* x2    = (float*)alloc((size_t)8192 * 1024 * 4);  // 32 MB
  bf16* hb     = qkvb;          // spans qkvb+yb (66MB >= 64MB needed)

  // weight prep
  transpose_cast_kernel<<<dim3(3072 / 32, 1024 / 32), dim3(32, 8), 0, stream>>>(W_qkv, Wt_qkv, 1024, 3072);
  transpose_cast_kernel<<<dim3(1024 / 32, 1024 / 32), dim3(32, 8), 0, stream>>>(W_o, Wt_o, 1024, 1024);
  transpose_cast_kernel<<<dim3(4096 / 32, 1024 / 32), dim3(32, 8), 0, stream>>>(W_fc, Wt_fc, 1024, 4096);
  transpose_cast_kernel<<<dim3(1024 / 32, 4096 / 32), dim3(32, 8), 0, stream>>>(W_proj, Wt_pr, 4096, 1024);
  cast_bf16_kernel<<<512, 256, 0, stream>>>(Er, Erb, 1024 * 128);

  // block
  ln_kernel<<<8192, 256, 0, stream>>>(x, ln1_g, ln1_b, xn);
  gemm_kernel<0><<<dim3(24, 64), 256, 0, stream>>>(xn, Wt_qkv, b_qkv, nullptr, qkvb, 8192, 3072, 1024);
  pack_kv_kernel<<<dim3(16, 8, 8), 256, 0, stream>>>(qkvb, Kpack, Vpack);
  flash_kernel<<<dim3(8, 8, 8), 256, 0, stream>>>(qkvb, Kpack, Vpack, Erb, yb);
  gemm_kernel<2><<<dim3(8, 64), 256, 0, stream>>>(yb, Wt_o, b_o, x, x2, 8192, 1024, 1024);
  ln_kernel<<<8192, 256, 0, stream>>>(x2, ln2_g, ln2_b, xn);
  gemm_kernel<1><<<dim3(32, 64), 256, 0, stream>>>(xn, Wt_fc, b_fc, nullptr, hb, 8192, 4096, 1024);
  gemm_kernel<2><<<dim3(8, 64), 256, 0, stream>>>(hb, Wt_pr, b_proj, x2, out, 8192, 1024, 4096);
}

// Round 4
// 616.537 us; speedup vs baseline: 1.1611x; 1.1611x over previous
//
#include <hip/hip_runtime.h>
#include <hip/hip_bf16.h>
#include <math.h>

// Problem constants
#define BB 8
#define LL 1024
#define DD 1024
#define FF 4096
#define NHH 8
#define HSS 128
#define SCALE 0.08838834764831845f  // 1/sqrt(128)
#define TRI(qi, kt) ((qi) * ((qi) + 1) / 2 + (kt))

typedef __bf16 bf16;
typedef __bf16 bf16x8 __attribute__((ext_vector_type(8)));
typedef float f32x4 __attribute__((ext_vector_type(4)));
typedef _Float16 f16;
typedef _Float16 f16x4 __attribute__((ext_vector_type(4)));

__device__ inline void async_copy16(const void* g, void* l) {
  __builtin_amdgcn_global_load_lds(
      (const __attribute__((address_space(1))) unsigned int*)g,
      (__attribute__((address_space(3))) unsigned int*)l, 16, 0, 0);
}

// ---------------------------------------------------------------------------
// Transpose + cast: W [K][N] fp32 -> Wt [N][K] bf16
// ---------------------------------------------------------------------------
__global__ __launch_bounds__(256)
void transpose_cast_kernel(const float* __restrict__ W, bf16* __restrict__ Wt,
                           int K, int N) {
  __shared__ float tile[32][33];
  int n0 = blockIdx.x * 32, k0 = blockIdx.y * 32;
  int tx = threadIdx.x, ty = threadIdx.y;
#pragma unroll
  for (int i = 0; i < 32; i += 8)
    tile[ty + i][tx] = W[(size_t)(k0 + ty + i) * N + n0 + tx];
  __syncthreads();
#pragma unroll
  for (int i = 0; i < 32; i += 8)
    Wt[(size_t)(n0 + ty + i) * K + k0 + tx] = (bf16)tile[tx][ty + i];
}

// ---------------------------------------------------------------------------
// pack_er: Er [1024][128] fp32 -> ErP fragment-major bf16.
// ErP[g*2048 + st*512 + lane*8 + j] = Er[g*16 + (lane&15)][st*32 + (lane>>4)*8 + j]
// so relband's B-fragment load for a 16-row group is ONE contiguous 1KB
// wave read instead of 64 scattered 16B chunks.
// ---------------------------------------------------------------------------
__global__ __launch_bounds__(256)
void pack_er_kernel(const float* __restrict__ Er, bf16* __restrict__ ErP) {
  int g = blockIdx.x, tid = threadIdx.x;
  int l15 = tid & 15, quad = (tid >> 4) & 3, st = tid >> 6;
  const float* src = Er + (size_t)(g * 16 + l15) * HSS + st * 32 + quad * 8;
  bf16* dst = ErP + (size_t)g * 2048 + tid * 8;
#pragma unroll
  for (int j = 0; j < 8; j++) dst[j] = (bf16)src[j];
}

// ---------------------------------------------------------------------------
// LayerNorm: x [8192][1024] fp32 -> out bf16
// ---------------------------------------------------------------------------
__global__ __launch_bounds__(256)
void ln_kernel(const float* __restrict__ x, const float* __restrict__ g,
               const float* __restrict__ bta, bf16* __restrict__ out) {
  int row = blockIdx.x;
  int tid = threadIdx.x;
  const float4 v = ((const float4*)(x + (size_t)row * DD))[tid];
  float s = v.x + v.y + v.z + v.w;
  float s2 = v.x * v.x + v.y * v.y + v.z * v.z + v.w * v.w;
#pragma unroll
  for (int o = 32; o > 0; o >>= 1) {
    s += __shfl_down(s, o);
    s2 += __shfl_down(s2, o);
  }
  __shared__ float a1[4], a2[4];
  int wave = tid >> 6;
  if ((tid & 63) == 0) { a1[wave] = s; a2[wave] = s2; }
  __syncthreads();
  s = a1[0] + a1[1] + a1[2] + a1[3];
  s2 = a2[0] + a2[1] + a2[2] + a2[3];
  float mu = s * (1.0f / DD);
  float rstd = rsqrtf(s2 * (1.0f / DD) - mu * mu + 1e-5f);
  float4 gv = ((const float4*)g)[tid];
  float4 bv = ((const float4*)bta)[tid];
  bf16* o4 = out + (size_t)row * DD + tid * 4;
  o4[0] = (bf16)((v.x - mu) * rstd * gv.x + bv.x);
  o4[1] = (bf16)((v.y - mu) * rstd * gv.y + bv.y);
  o4[2] = (bf16)((v.z - mu) * rstd * gv.z + bv.z);
  o4[3] = (bf16)((v.w - mu) * rstd * gv.w + bv.w);
}

// ---------------------------------------------------------------------------
// GEMM v3 (m97-exact structure): C[M][N] = A[M][K](bf16) * Bt[N][K](bf16)^T
// 128x128 tile, BK=64, SINGLE-buffered 32KB LDS, two barriers per K-step,
// global_load_lds width 16. Latency hiding comes from 3-5 resident blocks/CU
// (implicit wave-level overlap, m114) — NOT explicit dbuf (m132 regression).
// XOR chunk swizzle on the GLOBAL SOURCE re-applied on the ds_read side.
// EPI 0: -> bf16   EPI 1: gelu -> bf16   EPI 2: + res(fp32) -> fp32
// ---------------------------------------------------------------------------
template <int EPI>
__global__ __launch_bounds__(256)
void gemm_kernel(const bf16* __restrict__ A, const bf16* __restrict__ Bt,
                 const float* __restrict__ bias, const float* __restrict__ res,
                 void* __restrict__ Cout, int M, int N, int K) {
  __shared__ bf16 Als[128 * 64];
  __shared__ bf16 Bls[128 * 64];
  int tid = threadIdx.x;
  int wave = tid >> 6, lane = tid & 63;
  int l15 = lane & 15, quad = lane >> 4;

  int m0 = blockIdx.y * 128, n0 = blockIdx.x * 128;
  int wm = (wave >> 1) * 64, wn = (wave & 1) * 64;
  f32x4 acc[4][4] = {};

  const bf16* asrc[4];
  const bf16* bsrc[4];
  int ldso[4];
#pragma unroll
  for (int i = 0; i < 4; i++) {
    int u = i * 256 + tid;
    int row = u >> 3, c = u & 7;
    int g = c ^ (row & 7);
    asrc[i] = A + (size_t)(m0 + row) * K + g * 8;
    bsrc[i] = Bt + (size_t)(n0 + row) * K + g * 8;
    ldso[i] = u * 8;
  }

  for (int k0 = 0; k0 < K; k0 += 64) {
    __syncthreads();  // previous iteration's readers done before overwrite
#pragma unroll
    for (int i = 0; i < 4; i++) {
      async_copy16(asrc[i] + k0, &Als[ldso[i]]);
      async_copy16(bsrc[i] + k0, &Bls[ldso[i]]);
    }
    __syncthreads();  // compiler drains vmcnt(0) here: DMA complete

    bf16x8 af[2][4], bfr[2][4];
#pragma unroll
    for (int kk = 0; kk < 2; kk++) {
#pragma unroll
      for (int mt = 0; mt < 4; mt++) {
        int ra = wm + mt * 16 + l15;
        af[kk][mt] = *(const bf16x8*)&Als[ra * 64 + (((kk * 4 + quad) ^ (ra & 7)) << 3)];
        int rb = wn + mt * 16 + l15;
        bfr[kk][mt] = *(const bf16x8*)&Bls[rb * 64 + (((kk * 4 + quad) ^ (rb & 7)) << 3)];
      }
    }
#pragma unroll
    for (int kk = 0; kk < 2; kk++)
#pragma unroll
      for (int mt = 0; mt < 4; mt++)
#pragma unroll
        for (int nt = 0; nt < 4; nt++)
          acc[mt][nt] = __builtin_amdgcn_mfma_f32_16x16x32_bf16(af[kk][mt], bfr[kk][nt],
                                                                acc[mt][nt], 0, 0, 0);
  }

#pragma unroll
  for (int mt = 0; mt < 4; mt++) {
#pragma unroll
    for (int nt = 0; nt < 4; nt++) {
      int col = n0 + wn + nt * 16 + l15;
      float bv = bias[col];
#pragma unroll
      for (int r = 0; r < 4; r++) {
        int row = m0 + wm + mt * 16 + quad * 4 + r;
        float v = acc[mt][nt][r] + bv;
        if (EPI == 1) v = 0.5f * v * (1.0f + erff(v * 0.7071067811865475f));
        if (EPI == 2) {
          v += res[(size_t)row * N + col];
          ((float*)Cout)[(size_t)row * N + col] = v;
        } else {
          ((bf16*)Cout)[(size_t)row * N + col] = (bf16)v;
        }
      }
    }
  }
}

// ---------------------------------------------------------------------------
// pack_kv: per (b,h,kt) repack K into [kk][chunk^swizzle] and V transposed
// into [d][chunk^swizzle], 16B chunks, so flash can DMA-stage with
// global_load_lds and read fragments conflict-free.
// ---------------------------------------------------------------------------
__global__ __launch_bounds__(256)
void pack_kv_kernel(const bf16* __restrict__ qkv, bf16* __restrict__ Kpack,
                    bf16* __restrict__ Vpack) {
  __shared__ bf16 Vst[64][132];  // raw V tile [kk][d], padded
  int kt = blockIdx.x, h = blockIdx.y, b = blockIdx.z;
  int tid = threadIdx.x;
  const size_t rs = 3 * DD;
  const bf16* kb = qkv + (size_t)b * LL * rs + (size_t)(kt * 64) * rs + DD + h * HSS;
  const bf16* vb = kb + DD;
  bf16* kp = Kpack + ((size_t)(b * NHH + h) * 16 + kt) * (64 * 128);
  bf16* vp = Vpack + ((size_t)(b * NHH + h) * 16 + kt) * (128 * 64);
#pragma unroll
  for (int i = 0; i < 4; i++) {
    int u = i * 256 + tid;
    int kk = u >> 4, c = u & 15;
    // K: element (kk,d): chunk c=d>>3 stored at (c ^ (kk&15))
    bf16x8 kv = *(const bf16x8*)(kb + (size_t)kk * rs + c * 8);
    *(bf16x8*)(kp + kk * 128 + ((c ^ kk) & 15) * 8) = kv;
    // V raw stage for transpose
    *(bf16x8*)&Vst[kk][c * 8] = *(const bf16x8*)(vb + (size_t)kk * rs + c * 8);
  }
  __syncthreads();
#pragma unroll
  for (int i = 0; i < 4; i++) {
    int u = i * 256 + tid;
    int d = u >> 3, c = u & 7;  // V^T row d, kk-chunk c (kk = c*8+j)
    bf16x8 t;
#pragma unroll
    for (int j = 0; j < 8; j++) t[j] = Vst[c * 8 + j][d];
    *(bf16x8*)(vp + d * 64 + ((c ^ (d & 7))) * 8) = t;
  }
}

// ---------------------------------------------------------------------------
// relband v4: paired q-tiles (block does qb = x and 15-x -> 17 k-tiles,
// grid 512 uniform). Q fragments loaded ONCE per q-tile (was: per tile).
// Er read from fragment-major ErP -> each B-fragment is one contiguous 1KB
// wave load (was: 64 scattered 16B chunks). m_base is 16-aligned so
// fragments are whole 16-row groups; group-clamp g<=63 (g>=64 fragments
// feed only causally-masked slots). Gather + store identical to v3.
// ---------------------------------------------------------------------------
__global__ __launch_bounds__(256)
void relband_kernel(const bf16* __restrict__ qkv, const bf16* __restrict__ ErP,
                    f16* __restrict__ band) {
  int tid = threadIdx.x, wave = tid >> 6, lane = tid & 63;
  int l15 = lane & 15, quad = lane >> 4;
  int h = blockIdx.y, b = blockIdx.z;
  const size_t rs = 3 * DD;
  const bf16* qbase = qkv + (size_t)b * LL * rs + h * HSS;
  f16* bbase = band + (size_t)(b * NHH + h) * (136 * 4096);

#pragma unroll 1
  for (int ph = 0; ph < 2; ph++) {
    int qb = ph ? 15 - blockIdx.x : blockIdx.x;
    int qw0 = qb * 64 + wave * 16;

    bf16x8 qf[4];
#pragma unroll
    for (int st = 0; st < 4; st++)
      qf[st] = *(const bf16x8*)(qbase + (size_t)(qw0 + l15) * rs + st * 32 + quad * 8);

#pragma unroll 1
    for (int kt = 0; kt <= qb; kt++) {
      int k0 = kt * 64;
      int kmax_off = qw0 + 15 - k0;  // wave-uniform, >= 15
      int m_base = 1008 - qw0 + k0;  // >= 0, multiple of 16
      int gb = m_base >> 4;
      int ntR = (kmax_off >> 4) + 1;
      if (ntR > 4) ntR = 4;

      // R tiles in C-layout: rr[n][rg] = R[q=qw0+quad*4+rg][m=m_base+n*16+l15]
      f32x4 rr[5] = {};
#pragma unroll
      for (int n = 0; n < 5; n++) {
        if (n <= ntR) {
          int g = gb + n;
          if (g > 63) g = 63;  // g>=64: all elems m>1023 -> masked downstream
          const bf16* ep = ErP + (size_t)g * 2048 + lane * 8;
#pragma unroll
          for (int st = 0; st < 4; st++) {
            bf16x8 ef = *(const bf16x8*)(ep + st * 512);
            rr[n] = __builtin_amdgcn_mfma_f32_16x16x32_bf16(qf[st], ef, rr[n], 0, 0, 0);
          }
        }
      }

      // diagonal gather: Srel[q][k] = R[q][m], m = 1023-q+k  (c = 15-qloc+koff)
      f16x4 sf[4];
#pragma unroll
      for (int rg = 0; rg < 4; rg++) {
        int qloc = quad * 4 + rg;
        int tt = 15 - qloc + l15;           // 0..30
        int src = (lane & 48) | (tt & 15);  // same quad-row, rotated col
        float shv[5];
#pragma unroll
        for (int n = 0; n < 5; n++)
          shv[n] = (n <= ntR) ? __shfl(rr[n][rg], src) : 0.f;
#pragma unroll
        for (int nt = 0; nt < 4; nt++)
          sf[nt][rg] = (f16)((tt & 16) ? shv[nt + 1] : shv[nt]);
      }
      // coalesced fragment store (512B per wave store)
      f16* tb = bbase + (size_t)TRI(qb, kt) * 4096;
#pragma unroll
      for (int nt = 0; nt < 4; nt++)
        if (nt * 16 <= kmax_off)
          *(f16x4*)(tb + (wave * 4 + nt) * 256 + l15 * 16 + quad * 4) = sf[nt];
    }
  }
}

// ---------------------------------------------------------------------------
// Flash attention v6 (R2-proven): balanced pairing + LDS double-buffered K/V
// DMA (prefetch kt+1 during compute of kt; one barrier per tile; band loads
// issued before DMA so their vmcnt wait doesn't drain the prefetch).
// ---------------------------------------------------------------------------
__global__ __launch_bounds__(256)
void flash_kernel(const bf16* __restrict__ qkv, const bf16* __restrict__ Kpack,
                  const bf16* __restrict__ Vpack, const f16* __restrict__ band,
                  bf16* __restrict__ y) {
  __shared__ bf16 Kls[2][64 * 128];  // [kk][chunk^kk swizzle], double-buffered
  __shared__ bf16 Vls[2][128 * 64];  // [d][chunk^d swizzle], double-buffered
  __shared__ bf16 Pls[4][16][72];

  int tid = threadIdx.x, wave = tid >> 6, lane = tid & 63;
  int l15 = lane & 15, quad = lane >> 4;
  int h = blockIdx.y, b = blockIdx.z;

  const size_t rs = 3 * DD;
  const bf16* qbase = qkv + (size_t)b * LL * rs + h * HSS;
  const bf16* kp = Kpack + (size_t)(b * NHH + h) * 16 * (64 * 128);
  const bf16* vp = Vpack + (size_t)(b * NHH + h) * 16 * (128 * 64);
  const f16* bnd = band + (size_t)(b * NHH + h) * (136 * 4096);

  int buf = 0;  // global tile parity across both phases
#pragma unroll 1
  for (int ph = 0; ph < 2; ph++) {
    int qb = ph ? 15 - blockIdx.x : blockIdx.x;
    int qw0 = qb * 64 + wave * 16;
    int nkt = qb + 1;

    bf16x8 qf[4];
#pragma unroll
    for (int st = 0; st < 4; st++)
      qf[st] = *(const bf16x8*)(qbase + (size_t)(qw0 + l15) * rs + st * 32 + quad * 8);

    // prologue DMA: tile 0 of this phase into current buffer
    {
      const bf16* ks = kp;
      const bf16* vs = vp;
#pragma unroll
      for (int i = 0; i < 4; i++) {
        int off = (wave * 4 + i) * 512 + lane * 8;
        async_copy16(ks + off, &Kls[buf][off]);
        async_copy16(vs + off, &Vls[buf][off]);
      }
    }

    f32x4 o[8] = {};
    float mrow[4] = {-INFINITY, -INFINITY, -INFINITY, -INFINITY};
    float lrow[4] = {0.f, 0.f, 0.f, 0.f};

#pragma unroll 1
    for (int kt = 0; kt < nkt; kt++) {
      int k0 = kt * 64;
      int kmax_off = qw0 + 15 - k0;  // wave-uniform
      __syncthreads();  // drains DMA for tile kt; prev-tile readers done

      // Srel band fragments first (in-order vmcnt retire: waiting on these
      // does not drain the prefetch DMA issued below)
      const f16* tb = bnd + (size_t)TRI(qb, kt) * 4096;
      f16x4 srl[4] = {};
#pragma unroll
      for (int nt = 0; nt < 4; nt++)
        if (nt * 16 <= kmax_off)
          srl[nt] = *(const f16x4*)(tb + (wave * 4 + nt) * 256 + l15 * 16 + quad * 4);

      // prefetch DMA: tile kt+1 into alternate buffer
      if (kt + 1 < nkt) {
        const bf16* ks = kp + (size_t)(kt + 1) * (64 * 128);
        const bf16* vs = vp + (size_t)(kt + 1) * (128 * 64);
#pragma unroll
        for (int i = 0; i < 4; i++) {
          int off = (wave * 4 + i) * 512 + lane * 8;
          async_copy16(ks + off, &Kls[buf ^ 1][off]);
          async_copy16(vs + off, &Vls[buf ^ 1][off]);
        }
      }

      // S = Q K^T
      f32x4 sa[4] = {};
#pragma unroll
      for (int nt = 0; nt < 4; nt++) {
        if (nt * 16 <= kmax_off) {
          int kk = nt * 16 + l15;
#pragma unroll
          for (int st = 0; st < 4; st++) {
            bf16x8 kf = *(const bf16x8*)&Kls[buf][kk * 128 + (((st * 4 + quad) ^ l15) & 15) * 8];
            sa[nt] = __builtin_amdgcn_mfma_f32_16x16x32_bf16(qf[st], kf, sa[nt], 0, 0, 0);
          }
        }
      }

      // combine + mask + row max
      float pmx[4] = {-INFINITY, -INFINITY, -INFINITY, -INFINITY};
#pragma unroll
      for (int nt = 0; nt < 4; nt++) {
        if (nt * 16 <= kmax_off) {
          int kg = k0 + nt * 16 + l15;
#pragma unroll
          for (int rg = 0; rg < 4; rg++) {
            int qg = qw0 + quad * 4 + rg;
            float v = (sa[nt][rg] + (float)srl[nt][rg]) * SCALE;
            v = (kg <= qg) ? v : -INFINITY;
            sa[nt][rg] = v;
            pmx[rg] = fmaxf(pmx[rg], v);
          }
        } else {
#pragma unroll
          for (int rg = 0; rg < 4; rg++) sa[nt][rg] = -INFINITY;
        }
      }

      // online softmax (per 16-lane row group)
#pragma unroll
      for (int rg = 0; rg < 4; rg++) {
        float v = pmx[rg];
        v = fmaxf(v, __shfl_xor(v, 1));
        v = fmaxf(v, __shfl_xor(v, 2));
        v = fmaxf(v, __shfl_xor(v, 4));
        v = fmaxf(v, __shfl_xor(v, 8));
        float mnew = fmaxf(mrow[rg], v);
        float alpha = __expf(mrow[rg] - mnew);
        mrow[rg] = mnew;
        lrow[rg] *= alpha;
#pragma unroll
        for (int nt = 0; nt < 8; nt++) o[nt][rg] *= alpha;
        pmx[rg] = mnew;
      }
      float ls[4] = {0.f, 0.f, 0.f, 0.f};
#pragma unroll
      for (int nt = 0; nt < 4; nt++)
#pragma unroll
        for (int rg = 0; rg < 4; rg++) {
          float p = __expf(sa[nt][rg] - pmx[rg]);
          ls[rg] += p;
          Pls[wave][quad * 4 + rg][nt * 16 + l15] = (bf16)p;
        }
#pragma unroll
      for (int rg = 0; rg < 4; rg++) {
        float v = ls[rg];
        v += __shfl_xor(v, 1);
        v += __shfl_xor(v, 2);
        v += __shfl_xor(v, 4);
        v += __shfl_xor(v, 8);
        lrow[rg] += v;
      }
      // Pls is per-wave: same-wave DS ordering suffices, no barrier

      // O += P @ V
      bf16x8 pf[2];
#pragma unroll
      for (int s2 = 0; s2 < 2; s2++)
        pf[s2] = *(const bf16x8*)&Pls[wave][l15][s2 * 32 + quad * 8];
#pragma unroll
      for (int nt = 0; nt < 8; nt++) {
        int d = nt * 16 + l15;
#pragma unroll
        for (int s2 = 0; s2 < 2; s2++) {
          if (s2 * 32 <= kmax_off) {
            bf16x8 vf = *(const bf16x8*)&Vls[buf][d * 64 + (((s2 * 4 + quad) ^ (l15 & 7)) & 7) * 8];
            o[nt] = __builtin_amdgcn_mfma_f32_16x16x32_bf16(pf[s2], vf, o[nt], 0, 0, 0);
          }
        }
      }
      buf ^= 1;
    }

    // finalize phase: O / l -> y[b, q, h*128 + d] bf16
#pragma unroll
    for (int rg = 0; rg < 4; rg++) {
      float inv = 1.0f / lrow[rg];
      int qg = qw0 + quad * 4 + rg;
      bf16* yr = y + ((size_t)b * LL + qg) * DD + h * HSS;
#pragma unroll
      for (int nt = 0; nt < 8; nt++) yr[nt * 16 + l15] = (bf16)(o[nt][rg] * inv);
    }
  }
}

// ---------------------------------------------------------------------------
extern "C" void kernel_launch(void* const* d_in, const int* in_sizes, int n_in,
                              void* d_out, int out_size, void* d_ws, size_t ws_size,
                              hipStream_t stream) {
  const float* x = (const float*)d_in[0];
  const float* W_qkv = (const float*)d_in[1];
  const float* b_qkv = (const float*)d_in[2];
  const float* W_o = (const float*)d_in[3];
  const float* b_o = (const float*)d_in[4];
  const float* Er = (const float*)d_in[5];
  const float* ln1_g = (const float*)d_in[6];
  const float* ln1_b = (const float*)d_in[7];
  const float* ln2_g = (const float*)d_in[8];
  const float* ln2_b = (const float*)d_in[9];
  const float* W_fc = (const float*)d_in[10];
  const float* b_fc = (const float*)d_in[11];
  const float* W_proj = (const float*)d_in[12];
  const float* b_proj = (const float*)d_in[13];
  float* out = (float*)d_out;

  char* p = (char*)d_ws;
  auto alloc = [&](size_t bytes) {
    char* r = p;
    p += (bytes + 255) & ~(size_t)255;
    return r;
  };
  bf16* Wt_qkv = (bf16*)alloc((size_t)3072 * 1024 * 2);
  bf16* Wt_o   = (bf16*)alloc((size_t)1024 * 1024 * 2);
  bf16* Wt_fc  = (bf16*)alloc((size_t)4096 * 1024 * 2);
  bf16* Wt_pr  = (bf16*)alloc((size_t)1024 * 4096 * 2);
  bf16* ErP    = (bf16*)alloc((size_t)1024 * 128 * 2);
  bf16* xn     = (bf16*)alloc((size_t)8192 * 1024 * 2);
  bf16* qkvb   = (bf16*)alloc((size_t)8192 * 3072 * 2);  // + yb = hb region
  bf16* yb     = (bf16*)alloc((size_t)8192 * 1024 * 2);  // must follow qkvb
  bf16* Kpack  = (bf16*)alloc((size_t)64 * 16 * 64 * 128 * 2);
  bf16* Vpack  = (bf16*)alloc((size_t)64 * 16 * 128 * 64 * 2);
  f16*  band   = (f16*)alloc((size_t)64 * 136 * 4096 * 2);  // 71.3 MB
  float* x2    = (float*)band;  // alias: band dead before x2 is written
  bf16* hb     = qkvb;          // spans qkvb+yb (66MB >= 64MB needed)

  // weight prep
  transpose_cast_kernel<<<dim3(3072 / 32, 1024 / 32), dim3(32, 8), 0, stream>>>(W_qkv, Wt_qkv, 1024, 3072);
  transpose_cast_kernel<<<dim3(1024 / 32, 1024 / 32), dim3(32, 8), 0, stream>>>(W_o, Wt_o, 1024, 1024);
  transpose_cast_kernel<<<dim3(4096 / 32, 1024 / 32), dim3(32, 8), 0, stream>>>(W_fc, Wt_fc, 1024, 4096);
  transpose_cast_kernel<<<dim3(1024 / 32, 4096 / 32), dim3(32, 8), 0, stream>>>(W_proj, Wt_pr, 4096, 1024);
  pack_er_kernel<<<64, 256, 0, stream>>>(Er, ErP);

  // block
  ln_kernel<<<8192, 256, 0, stream>>>(x, ln1_g, ln1_b, xn);
  gemm_kernel<0><<<dim3(24, 64), 256, 0, stream>>>(xn, Wt_qkv, b_qkv, nullptr, qkvb, 8192, 3072, 1024);
  pack_kv_kernel<<<dim3(16, 8, 8), 256, 0, stream>>>(qkvb, Kpack, Vpack);
  relband_kernel<<<dim3(8, 8, 8), 256, 0, stream>>>(qkvb, ErP, band);
  flash_kernel<<<dim3(8, 8, 8), 256, 0, stream>>>(qkvb, Kpack, Vpack, band, yb);
  gemm_kernel<2><<<dim3(8, 64), 256, 0, stream>>>(yb, Wt_o, b_o, x, x2, 8192, 1024, 1024);
  ln_kernel<<<8192, 256, 0, stream>>>(x2, ln2_g, ln2_b, xn);
  gemm_kernel<1><<<dim3(32, 64), 256, 0, stream>>>(xn, Wt_fc, b_fc, nullptr, hb, 8192, 4096, 1024);
  gemm_kernel<2><<<dim3(8, 64), 256, 0, stream>>>(hb, Wt_pr, b_proj, x2, out, 8192, 1024, 4096);
}

// Round 5
// 600.289 us; speedup vs baseline: 1.1925x; 1.0271x over previous
//
#include <hip/hip_runtime.h>
#include <hip/hip_bf16.h>
#include <math.h>

// Problem constants
#define BB 8
#define LL 1024
#define DD 1024
#define FF 4096
#define NHH 8
#define HSS 128
#define SCALE 0.08838834764831845f  // 1/sqrt(128)
#define TRI(qi, kt) ((qi) * ((qi) + 1) / 2 + (kt))

typedef __bf16 bf16;
typedef __bf16 bf16x8 __attribute__((ext_vector_type(8)));
typedef float f32x4 __attribute__((ext_vector_type(4)));
typedef _Float16 f16;
typedef _Float16 f16x4 __attribute__((ext_vector_type(4)));

__device__ inline void async_copy16(const void* g, void* l) {
  __builtin_amdgcn_global_load_lds(
      (const __attribute__((address_space(1))) unsigned int*)g,
      (__attribute__((address_space(3))) unsigned int*)l, 16, 0, 0);
}

#define FENCE() asm volatile("" ::: "memory")
#define BARRIER() do { FENCE(); __builtin_amdgcn_s_barrier(); FENCE(); } while (0)
#define VMCNT6() asm volatile("s_waitcnt vmcnt(6)" ::: "memory")

// ---------------------------------------------------------------------------
// Transpose + cast: W [K][N] fp32 -> Wt [N][K] bf16
// ---------------------------------------------------------------------------
__global__ __launch_bounds__(256)
void transpose_cast_kernel(const float* __restrict__ W, bf16* __restrict__ Wt,
                           int K, int N) {
  __shared__ float tile[32][33];
  int n0 = blockIdx.x * 32, k0 = blockIdx.y * 32;
  int tx = threadIdx.x, ty = threadIdx.y;
#pragma unroll
  for (int i = 0; i < 32; i += 8)
    tile[ty + i][tx] = W[(size_t)(k0 + ty + i) * N + n0 + tx];
  __syncthreads();
#pragma unroll
  for (int i = 0; i < 32; i += 8)
    Wt[(size_t)(n0 + ty + i) * K + k0 + tx] = (bf16)tile[tx][ty + i];
}

// ---------------------------------------------------------------------------
// pack_er: Er [1024][128] fp32 -> ErP fragment-major bf16.
// ---------------------------------------------------------------------------
__global__ __launch_bounds__(256)
void pack_er_kernel(const float* __restrict__ Er, bf16* __restrict__ ErP) {
  int g = blockIdx.x, tid = threadIdx.x;
  int l15 = tid & 15, quad = (tid >> 4) & 3, st = tid >> 6;
  const float* src = Er + (size_t)(g * 16 + l15) * HSS + st * 32 + quad * 8;
  bf16* dst = ErP + (size_t)g * 2048 + tid * 8;
#pragma unroll
  for (int j = 0; j < 8; j++) dst[j] = (bf16)src[j];
}

// ---------------------------------------------------------------------------
// LayerNorm: x [8192][1024] fp32 -> out bf16
// ---------------------------------------------------------------------------
__global__ __launch_bounds__(256)
void ln_kernel(const float* __restrict__ x, const float* __restrict__ g,
               const float* __restrict__ bta, bf16* __restrict__ out) {
  int row = blockIdx.x;
  int tid = threadIdx.x;
  const float4 v = ((const float4*)(x + (size_t)row * DD))[tid];
  float s = v.x + v.y + v.z + v.w;
  float s2 = v.x * v.x + v.y * v.y + v.z * v.z + v.w * v.w;
#pragma unroll
  for (int o = 32; o > 0; o >>= 1) {
    s += __shfl_down(s, o);
    s2 += __shfl_down(s2, o);
  }
  __shared__ float a1[4], a2[4];
  int wave = tid >> 6;
  if ((tid & 63) == 0) { a1[wave] = s; a2[wave] = s2; }
  __syncthreads();
  s = a1[0] + a1[1] + a1[2] + a1[3];
  s2 = a2[0] + a2[1] + a2[2] + a2[3];
  float mu = s * (1.0f / DD);
  float rstd = rsqrtf(s2 * (1.0f / DD) - mu * mu + 1e-5f);
  float4 gv = ((const float4*)g)[tid];
  float4 bv = ((const float4*)bta)[tid];
  bf16* o4 = out + (size_t)row * DD + tid * 4;
  o4[0] = (bf16)((v.x - mu) * rstd * gv.x + bv.x);
  o4[1] = (bf16)((v.y - mu) * rstd * gv.y + bv.y);
  o4[2] = (bf16)((v.z - mu) * rstd * gv.z + bv.z);
  o4[3] = (bf16)((v.w - mu) * rstd * gv.w + bv.w);
}

// ---------------------------------------------------------------------------
// GEMM 256x256 8-phase (T3+T4+T5 port): C = A[M][K] * Bt[N][K]^T + bias.
// 512 thr / 8 waves (2Mx4N), BK=64, 128 KiB LDS (2 dbuf x A+B 256x64).
// Per phase: one 128x128 C-quadrant (16 MFMA/wave) interleaved with ds-reads
// of only the changed operand half + ONE half-tile DMA stage; raw s_barrier
// (no vmcnt(0) drain); counted vmcnt(6) at ph1/ph3 only.
// Stage schedule (stage -> first read distance >= 4 phases):
//   ph0: B0(t+1)->buf^1   ph1: A1(t+1)->buf^1 [vmcnt6]
//   ph2: A0(t+2)->buf     ph3: B1(t+2)->buf   [vmcnt6]
// WAR safety: every stage dest's previous occupant had its last ds_read >= 1
// barrier earlier (rendezvous semantics). RAW: vmcnt ledger verified: prologue
// vmcnt(6) covers ph0/ph1 of t=0; each ph1/ph3 check covers the next 2 phases.
// EPI 0: -> bf16   EPI 1: gelu -> bf16
// ---------------------------------------------------------------------------
template <int EPI>
__global__ __launch_bounds__(512)
void gemm256_kernel(const bf16* __restrict__ A, const bf16* __restrict__ Bt,
                    const float* __restrict__ bias, void* __restrict__ Cout,
                    int M, int N, int K) {
  __shared__ bf16 Als[2][256 * 64];
  __shared__ bf16 Bls[2][256 * 64];
  int tid = threadIdx.x;
  int wave = tid >> 6, lane = tid & 63;
  int l15 = lane & 15, quad = lane >> 4;
  int wmi = wave >> 2, wni = wave & 3;
  int m0 = blockIdx.y * 256, n0 = blockIdx.x * 256;

  // staging: 2 chunks/thread per half-tile (128 rows x 64 cols = 16 KB)
  // chunk u: row rl=u>>3, lds chunk c=u&7 holds global chunk c^(rl&7)
  int u0 = tid, u1 = tid + 512;
  int r0 = u0 >> 3, c0 = ((u0 & 7) ^ (r0 & 7)) << 3;
  int r1 = u1 >> 3, c1 = ((u1 & 7) ^ (r1 & 7)) << 3;
  const bf16* aB0 = A + (size_t)(m0 + r0) * K + c0;
  const bf16* aB1 = A + (size_t)(m0 + r1) * K + c1;
  const bf16* bB0 = Bt + (size_t)(n0 + r0) * K + c0;
  const bf16* bB1 = Bt + (size_t)(n0 + r1) * K + c1;
  int d0 = u0 * 8, d1 = u1 * 8;

  auto stageA = [&](int b, int h, int t) {
    size_t off = (size_t)h * 128 * K + (size_t)t * 64;
    async_copy16(aB0 + off, &Als[b][h * 8192 + d0]);
    async_copy16(aB1 + off, &Als[b][h * 8192 + d1]);
  };
  auto stageB = [&](int b, int h, int t) {
    size_t off = (size_t)h * 128 * K + (size_t)t * 64;
    async_copy16(bB0 + off, &Bls[b][h * 8192 + d0]);
    async_copy16(bB1 + off, &Bls[b][h * 8192 + d1]);
  };

  f32x4 acc[8][4] = {};
  bf16x8 af[2][4], bfr[2][2];

  auto readA = [&](int b, int qm) {
#pragma unroll
    for (int kk = 0; kk < 2; kk++)
#pragma unroll
      for (int mt = 0; mt < 4; mt++) {
        int ra = qm * 128 + wmi * 64 + mt * 16 + l15;
        af[kk][mt] = *(const bf16x8*)&Als[b][ra * 64 + (((kk * 4 + quad) ^ (ra & 7)) << 3)];
      }
  };
  auto readB = [&](int b, int qn) {
#pragma unroll
    for (int kk = 0; kk < 2; kk++)
#pragma unroll
      for (int nt = 0; nt < 2; nt++) {
        int rb = qn * 128 + wni * 32 + nt * 16 + l15;
        bfr[kk][nt] = *(const bf16x8*)&Bls[b][rb * 64 + (((kk * 4 + quad) ^ (rb & 7)) << 3)];
      }
  };
  auto mfma16 = [&](int qm, int qn) {
    __builtin_amdgcn_s_setprio(1);
#pragma unroll
    for (int kk = 0; kk < 2; kk++)
#pragma unroll
      for (int mt = 0; mt < 4; mt++)
#pragma unroll
        for (int nt = 0; nt < 2; nt++)
          acc[qm * 4 + mt][qn * 2 + nt] = __builtin_amdgcn_mfma_f32_16x16x32_bf16(
              af[kk][mt], bfr[kk][nt], acc[qm * 4 + mt][qn * 2 + nt], 0, 0, 0);
    __builtin_amdgcn_s_setprio(0);
  };

  int nk = K >> 6;  // >= 3 required (K=1024 -> 16)
  // prologue issue order: A0(0) B0(0) B1(0) A1(0) A0(1) B1(1); wait oldest 3.
  stageA(0, 0, 0); stageB(0, 0, 0); stageB(0, 1, 0); stageA(0, 1, 0);
  stageA(1, 0, 1); stageB(1, 1, 1);
  VMCNT6();
  BARRIER();

  for (int t = 0; t < nk; t++) {
    int cur = t & 1;
    // ph0: quadrant (0,0)
    readA(cur, 0); readB(cur, 0);
    if (t + 1 < nk) stageB(cur ^ 1, 0, t + 1);
    BARRIER();
    mfma16(0, 0);
    BARRIER();
    // ph1: quadrant (0,1)
    readB(cur, 1);
    if (t + 1 < nk) stageA(cur ^ 1, 1, t + 1);
    VMCNT6();
    BARRIER();
    mfma16(0, 1);
    BARRIER();
    // ph2: quadrant (1,1)
    readA(cur, 1);
    if (t + 2 < nk) stageA(cur, 0, t + 2);
    BARRIER();
    mfma16(1, 1);
    BARRIER();
    // ph3: quadrant (1,0)
    readB(cur, 0);
    if (t + 2 < nk) stageB(cur, 1, t + 2);
    VMCNT6();
    BARRIER();
    mfma16(1, 0);
    BARRIER();
  }

  // epilogue: rows m0 + (MT>>2)*128 + wmi*64 + (MT&3)*16 + quad*4 + r
  //           cols n0 + (NT>>1)*128 + wni*32 + (NT&1)*16 + l15
#pragma unroll
  for (int MT = 0; MT < 8; MT++) {
#pragma unroll
    for (int NT = 0; NT < 4; NT++) {
      int col = n0 + (NT >> 1) * 128 + wni * 32 + (NT & 1) * 16 + l15;
      float bv = bias[col];
#pragma unroll
      for (int r = 0; r < 4; r++) {
        int row = m0 + (MT >> 2) * 128 + wmi * 64 + (MT & 3) * 16 + quad * 4 + r;
        float v = acc[MT][NT][r] + bv;
        if (EPI == 1) v = 0.5f * v * (1.0f + erff(v * 0.7071067811865475f));
        ((bf16*)Cout)[(size_t)row * N + col] = (bf16)v;
      }
    }
  }
}

// ---------------------------------------------------------------------------
// GEMM v3 (m97-exact structure), kept for N=1024 GEMMs (EPI 2).
// ---------------------------------------------------------------------------
template <int EPI>
__global__ __launch_bounds__(256)
void gemm_kernel(const bf16* __restrict__ A, const bf16* __restrict__ Bt,
                 const float* __restrict__ bias, const float* __restrict__ res,
                 void* __restrict__ Cout, int M, int N, int K) {
  __shared__ bf16 Als[128 * 64];
  __shared__ bf16 Bls[128 * 64];
  int tid = threadIdx.x;
  int wave = tid >> 6, lane = tid & 63;
  int l15 = lane & 15, quad = lane >> 4;

  int m0 = blockIdx.y * 128, n0 = blockIdx.x * 128;
  int wm = (wave >> 1) * 64, wn = (wave & 1) * 64;
  f32x4 acc[4][4] = {};

  const bf16* asrc[4];
  const bf16* bsrc[4];
  int ldso[4];
#pragma unroll
  for (int i = 0; i < 4; i++) {
    int u = i * 256 + tid;
    int row = u >> 3, c = u & 7;
    int g = c ^ (row & 7);
    asrc[i] = A + (size_t)(m0 + row) * K + g * 8;
    bsrc[i] = Bt + (size_t)(n0 + row) * K + g * 8;
    ldso[i] = u * 8;
  }

  for (int k0 = 0; k0 < K; k0 += 64) {
    __syncthreads();
#pragma unroll
    for (int i = 0; i < 4; i++) {
      async_copy16(asrc[i] + k0, &Als[ldso[i]]);
      async_copy16(bsrc[i] + k0, &Bls[ldso[i]]);
    }
    __syncthreads();

    bf16x8 af[2][4], bfr[2][4];
#pragma unroll
    for (int kk = 0; kk < 2; kk++) {
#pragma unroll
      for (int mt = 0; mt < 4; mt++) {
        int ra = wm + mt * 16 + l15;
        af[kk][mt] = *(const bf16x8*)&Als[ra * 64 + (((kk * 4 + quad) ^ (ra & 7)) << 3)];
        int rb = wn + mt * 16 + l15;
        bfr[kk][mt] = *(const bf16x8*)&Bls[rb * 64 + (((kk * 4 + quad) ^ (rb & 7)) << 3)];
      }
    }
#pragma unroll
    for (int kk = 0; kk < 2; kk++)
#pragma unroll
      for (int mt = 0; mt < 4; mt++)
#pragma unroll
        for (int nt = 0; nt < 4; nt++)
          acc[mt][nt] = __builtin_amdgcn_mfma_f32_16x16x32_bf16(af[kk][mt], bfr[kk][nt],
                                                                acc[mt][nt], 0, 0, 0);
  }

#pragma unroll
  for (int mt = 0; mt < 4; mt++) {
#pragma unroll
    for (int nt = 0; nt < 4; nt++) {
      int col = n0 + wn + nt * 16 + l15;
      float bv = bias[col];
#pragma unroll
      for (int r = 0; r < 4; r++) {
        int row = m0 + wm + mt * 16 + quad * 4 + r;
        float v = acc[mt][nt][r] + bv;
        if (EPI == 1) v = 0.5f * v * (1.0f + erff(v * 0.7071067811865475f));
        if (EPI == 2) {
          v += res[(size_t)row * N + col];
          ((float*)Cout)[(size_t)row * N + col] = v;
        } else {
          ((bf16*)Cout)[(size_t)row * N + col] = (bf16)v;
        }
      }
    }
  }
}

// ---------------------------------------------------------------------------
// pack_kv: per (b,h,kt) repack K into [kk][chunk^swizzle] and V transposed
// into [d][chunk^swizzle], 16B chunks.
// ---------------------------------------------------------------------------
__global__ __launch_bounds__(256)
void pack_kv_kernel(const bf16* __restrict__ qkv, bf16* __restrict__ Kpack,
                    bf16* __restrict__ Vpack) {
  __shared__ bf16 Vst[64][132];
  int kt = blockIdx.x, h = blockIdx.y, b = blockIdx.z;
  int tid = threadIdx.x;
  const size_t rs = 3 * DD;
  const bf16* kb = qkv + (size_t)b * LL * rs + (size_t)(kt * 64) * rs + DD + h * HSS;
  const bf16* vb = kb + DD;
  bf16* kp = Kpack + ((size_t)(b * NHH + h) * 16 + kt) * (64 * 128);
  bf16* vp = Vpack + ((size_t)(b * NHH + h) * 16 + kt) * (128 * 64);
#pragma unroll
  for (int i = 0; i < 4; i++) {
    int u = i * 256 + tid;
    int kk = u >> 4, c = u & 15;
    bf16x8 kv = *(const bf16x8*)(kb + (size_t)kk * rs + c * 8);
    *(bf16x8*)(kp + kk * 128 + ((c ^ kk) & 15) * 8) = kv;
    *(bf16x8*)&Vst[kk][c * 8] = *(const bf16x8*)(vb + (size_t)kk * rs + c * 8);
  }
  __syncthreads();
#pragma unroll
  for (int i = 0; i < 4; i++) {
    int u = i * 256 + tid;
    int d = u >> 3, c = u & 7;
    bf16x8 t;
#pragma unroll
    for (int j = 0; j < 8; j++) t[j] = Vst[c * 8 + j][d];
    *(bf16x8*)(vp + d * 64 + ((c ^ (d & 7))) * 8) = t;
  }
}

// ---------------------------------------------------------------------------
// relband v4: paired q-tiles, fragment-major ErP loads, Q loaded once/q-tile.
// ---------------------------------------------------------------------------
__global__ __launch_bounds__(256)
void relband_kernel(const bf16* __restrict__ qkv, const bf16* __restrict__ ErP,
                    f16* __restrict__ band) {
  int tid = threadIdx.x, wave = tid >> 6, lane = tid & 63;
  int l15 = lane & 15, quad = lane >> 4;
  int h = blockIdx.y, b = blockIdx.z;
  const size_t rs = 3 * DD;
  const bf16* qbase = qkv + (size_t)b * LL * rs + h * HSS;
  f16* bbase = band + (size_t)(b * NHH + h) * (136 * 4096);

#pragma unroll 1
  for (int ph = 0; ph < 2; ph++) {
    int qb = ph ? 15 - blockIdx.x : blockIdx.x;
    int qw0 = qb * 64 + wave * 16;

    bf16x8 qf[4];
#pragma unroll
    for (int st = 0; st < 4; st++)
      qf[st] = *(const bf16x8*)(qbase + (size_t)(qw0 + l15) * rs + st * 32 + quad * 8);

#pragma unroll 1
    for (int kt = 0; kt <= qb; kt++) {
      int k0 = kt * 64;
      int kmax_off = qw0 + 15 - k0;
      int m_base = 1008 - qw0 + k0;
      int gb = m_base >> 4;
      int ntR = (kmax_off >> 4) + 1;
      if (ntR > 4) ntR = 4;

      f32x4 rr[5] = {};
#pragma unroll
      for (int n = 0; n < 5; n++) {
        if (n <= ntR) {
          int g = gb + n;
          if (g > 63) g = 63;
          const bf16* ep = ErP + (size_t)g * 2048 + lane * 8;
#pragma unroll
          for (int st = 0; st < 4; st++) {
            bf16x8 ef = *(const bf16x8*)(ep + st * 512);
            rr[n] = __builtin_amdgcn_mfma_f32_16x16x32_bf16(qf[st], ef, rr[n], 0, 0, 0);
          }
        }
      }

      f16x4 sf[4];
#pragma unroll
      for (int rg = 0; rg < 4; rg++) {
        int qloc = quad * 4 + rg;
        int tt = 15 - qloc + l15;
        int src = (lane & 48) | (tt & 15);
        float shv[5];
#pragma unroll
        for (int n = 0; n < 5; n++)
          shv[n] = (n <= ntR) ? __shfl(rr[n][rg], src) : 0.f;
#pragma unroll
        for (int nt = 0; nt < 4; nt++)
          sf[nt][rg] = (f16)((tt & 16) ? shv[nt + 1] : shv[nt]);
      }
      f16* tb = bbase + (size_t)TRI(qb, kt) * 4096;
#pragma unroll
      for (int nt = 0; nt < 4; nt++)
        if (nt * 16 <= kmax_off)
          *(f16x4*)(tb + (wave * 4 + nt) * 256 + l15 * 16 + quad * 4) = sf[nt];
    }
  }
}

// ---------------------------------------------------------------------------
// Flash attention v6 (R2-proven): balanced pairing + LDS double-buffered K/V
// DMA.
// ---------------------------------------------------------------------------
__global__ __launch_bounds__(256)
void flash_kernel(const bf16* __restrict__ qkv, const bf16* __restrict__ Kpack,
                  const bf16* __restrict__ Vpack, const f16* __restrict__ band,
                  bf16* __restrict__ y) {
  __shared__ bf16 Kls[2][64 * 128];
  __shared__ bf16 Vls[2][128 * 64];
  __shared__ bf16 Pls[4][16][72];

  int tid = threadIdx.x, wave = tid >> 6, lane = tid & 63;
  int l15 = lane & 15, quad = lane >> 4;
  int h = blockIdx.y, b = blockIdx.z;

  const size_t rs = 3 * DD;
  const bf16* qbase = qkv + (size_t)b * LL * rs + h * HSS;
  const bf16* kp = Kpack + (size_t)(b * NHH + h) * 16 * (64 * 128);
  const bf16* vp = Vpack + (size_t)(b * NHH + h) * 16 * (128 * 64);
  const f16* bnd = band + (size_t)(b * NHH + h) * (136 * 4096);

  int buf = 0;
#pragma unroll 1
  for (int ph = 0; ph < 2; ph++) {
    int qb = ph ? 15 - blockIdx.x : blockIdx.x;
    int qw0 = qb * 64 + wave * 16;
    int nkt = qb + 1;

    bf16x8 qf[4];
#pragma unroll
    for (int st = 0; st < 4; st++)
      qf[st] = *(const bf16x8*)(qbase + (size_t)(qw0 + l15) * rs + st * 32 + quad * 8);

    {
      const bf16* ks = kp;
      const bf16* vs = vp;
#pragma unroll
      for (int i = 0; i < 4; i++) {
        int off = (wave * 4 + i) * 512 + lane * 8;
        async_copy16(ks + off, &Kls[buf][off]);
        async_copy16(vs + off, &Vls[buf][off]);
      }
    }

    f32x4 o[8] = {};
    float mrow[4] = {-INFINITY, -INFINITY, -INFINITY, -INFINITY};
    float lrow[4] = {0.f, 0.f, 0.f, 0.f};

#pragma unroll 1
    for (int kt = 0; kt < nkt; kt++) {
      int k0 = kt * 64;
      int kmax_off = qw0 + 15 - k0;
      __syncthreads();

      const f16* tb = bnd + (size_t)TRI(qb, kt) * 4096;
      f16x4 srl[4] = {};
#pragma unroll
      for (int nt = 0; nt < 4; nt++)
        if (nt * 16 <= kmax_off)
          srl[nt] = *(const f16x4*)(tb + (wave * 4 + nt) * 256 + l15 * 16 + quad * 4);

      if (kt + 1 < nkt) {
        const bf16* ks = kp + (size_t)(kt + 1) * (64 * 128);
        const bf16* vs = vp + (size_t)(kt + 1) * (128 * 64);
#pragma unroll
        for (int i = 0; i < 4; i++) {
          int off = (wave * 4 + i) * 512 + lane * 8;
          async_copy16(ks + off, &Kls[buf ^ 1][off]);
          async_copy16(vs + off, &Vls[buf ^ 1][off]);
        }
      }

      f32x4 sa[4] = {};
#pragma unroll
      for (int nt = 0; nt < 4; nt++) {
        if (nt * 16 <= kmax_off) {
          int kk = nt * 16 + l15;
#pragma unroll
          for (int st = 0; st < 4; st++) {
            bf16x8 kf = *(const bf16x8*)&Kls[buf][kk * 128 + (((st * 4 + quad) ^ l15) & 15) * 8];
            sa[nt] = __builtin_amdgcn_mfma_f32_16x16x32_bf16(qf[st], kf, sa[nt], 0, 0, 0);
          }
        }
      }

      float pmx[4] = {-INFINITY, -INFINITY, -INFINITY, -INFINITY};
#pragma unroll
      for (int nt = 0; nt < 4; nt++) {
        if (nt * 16 <= kmax_off) {
          int kg = k0 + nt * 16 + l15;
#pragma unroll
          for (int rg = 0; rg < 4; rg++) {
            int qg = qw0 + quad * 4 + rg;
            float v = (sa[nt][rg] + (float)srl[nt][rg]) * SCALE;
            v = (kg <= qg) ? v : -INFINITY;
            sa[nt][rg] = v;
            pmx[rg] = fmaxf(pmx[rg], v);
          }
        } else {
#pragma unroll
          for (int rg = 0; rg < 4; rg++) sa[nt][rg] = -INFINITY;
        }
      }

#pragma unroll
      for (int rg = 0; rg < 4; rg++) {
        float v = pmx[rg];
        v = fmaxf(v, __shfl_xor(v, 1));
        v = fmaxf(v, __shfl_xor(v, 2));
        v = fmaxf(v, __shfl_xor(v, 4));
        v = fmaxf(v, __shfl_xor(v, 8));
        float mnew = fmaxf(mrow[rg], v);
        float alpha = __expf(mrow[rg] - mnew);
        mrow[rg] = mnew;
        lrow[rg] *= alpha;
#pragma unroll
        for (int nt = 0; nt < 8; nt++) o[nt][rg] *= alpha;
        pmx[rg] = mnew;
      }
      float ls[4] = {0.f, 0.f, 0.f, 0.f};
#pragma unroll
      for (int nt = 0; nt < 4; nt++)
#pragma unroll
        for (int rg = 0; rg < 4; rg++) {
          float p = __expf(sa[nt][rg] - pmx[rg]);
          ls[rg] += p;
          Pls[wave][quad * 4 + rg][nt * 16 + l15] = (bf16)p;
        }
#pragma unroll
      for (int rg = 0; rg < 4; rg++) {
        float v = ls[rg];
        v += __shfl_xor(v, 1);
        v += __shfl_xor(v, 2);
        v += __shfl_xor(v, 4);
        v += __shfl_xor(v, 8);
        lrow[rg] += v;
      }

      bf16x8 pf[2];
#pragma unroll
      for (int s2 = 0; s2 < 2; s2++)
        pf[s2] = *(const bf16x8*)&Pls[wave][l15][s2 * 32 + quad * 8];
#pragma unroll
      for (int nt = 0; nt < 8; nt++) {
        int d = nt * 16 + l15;
#pragma unroll
        for (int s2 = 0; s2 < 2; s2++) {
          if (s2 * 32 <= kmax_off) {
            bf16x8 vf = *(const bf16x8*)&Vls[buf][d * 64 + (((s2 * 4 + quad) ^ (l15 & 7)) & 7) * 8];
            o[nt] = __builtin_amdgcn_mfma_f32_16x16x32_bf16(pf[s2], vf, o[nt], 0, 0, 0);
          }
        }
      }
      buf ^= 1;
    }

#pragma unroll
    for (int rg = 0; rg < 4; rg++) {
      float inv = 1.0f / lrow[rg];
      int qg = qw0 + quad * 4 + rg;
      bf16* yr = y + ((size_t)b * LL + qg) * DD + h * HSS;
#pragma unroll
      for (int nt = 0; nt < 8; nt++) yr[nt * 16 + l15] = (bf16)(o[nt][rg] * inv);
    }
  }
}

// ---------------------------------------------------------------------------
extern "C" void kernel_launch(void* const* d_in, const int* in_sizes, int n_in,
                              void* d_out, int out_size, void* d_ws, size_t ws_size,
                              hipStream_t stream) {
  const float* x = (const float*)d_in[0];
  const float* W_qkv = (const float*)d_in[1];
  const float* b_qkv = (const float*)d_in[2];
  const float* W_o = (const float*)d_in[3];
  const float* b_o = (const float*)d_in[4];
  const float* Er = (const float*)d_in[5];
  const float* ln1_g = (const float*)d_in[6];
  const float* ln1_b = (const float*)d_in[7];
  const float* ln2_g = (const float*)d_in[8];
  const float* ln2_b = (const float*)d_in[9];
  const float* W_fc = (const float*)d_in[10];
  const float* b_fc = (const float*)d_in[11];
  const float* W_proj = (const float*)d_in[12];
  const float* b_proj = (const float*)d_in[13];
  float* out = (float*)d_out;

  char* p = (char*)d_ws;
  auto alloc = [&](size_t bytes) {
    char* r = p;
    p += (bytes + 255) & ~(size_t)255;
    return r;
  };
  bf16* Wt_qkv = (bf16*)alloc((size_t)3072 * 1024 * 2);
  bf16* Wt_o   = (bf16*)alloc((size_t)1024 * 1024 * 2);
  bf16* Wt_fc  = (bf16*)alloc((size_t)4096 * 1024 * 2);
  bf16* Wt_pr  = (bf16*)alloc((size_t)1024 * 4096 * 2);
  bf16* ErP    = (bf16*)alloc((size_t)1024 * 128 * 2);
  bf16* xn     = (bf16*)alloc((size_t)8192 * 1024 * 2);
  bf16* qkvb   = (bf16*)alloc((size_t)8192 * 3072 * 2);  // + yb = hb region
  bf16* yb     = (bf16*)alloc((size_t)8192 * 1024 * 2);  // must follow qkvb
  bf16* Kpack  = (bf16*)alloc((size_t)64 * 16 * 64 * 128 * 2);
  bf16* Vpack  = (bf16*)alloc((size_t)64 * 16 * 128 * 64 * 2);
  f16*  band   = (f16*)alloc((size_t)64 * 136 * 4096 * 2);  // 71.3 MB
  float* x2    = (float*)band;  // alias: band dead before x2 is written
  bf16* hb     = qkvb;          // spans qkvb+yb (66MB >= 64MB needed)

  // weight prep
  transpose_cast_kernel<<<dim3(3072 / 32, 1024 / 32), dim3(32, 8), 0, stream>>>(W_qkv, Wt_qkv, 1024, 3072);
  transpose_cast_kernel<<<dim3(1024 / 32, 1024 / 32), dim3(32, 8), 0, stream>>>(W_o, Wt_o, 1024, 1024);
  transpose_cast_kernel<<<dim3(4096 / 32, 1024 / 32), dim3(32, 8), 0, stream>>>(W_fc, Wt_fc, 1024, 4096);
  transpose_cast_kernel<<<dim3(1024 / 32, 4096 / 32), dim3(32, 8), 0, stream>>>(W_proj, Wt_pr, 4096, 1024);
  pack_er_kernel<<<64, 256, 0, stream>>>(Er, ErP);

  // block
  ln_kernel<<<8192, 256, 0, stream>>>(x, ln1_g, ln1_b, xn);
  gemm256_kernel<0><<<dim3(12, 32), 512, 0, stream>>>(xn, Wt_qkv, b_qkv, qkvb, 8192, 3072, 1024);
  pack_kv_kernel<<<dim3(16, 8, 8), 256, 0, stream>>>(qkvb, Kpack, Vpack);
  relband_kernel<<<dim3(8, 8, 8), 256, 0, stream>>>(qkvb, ErP, band);
  flash_kernel<<<dim3(8, 8, 8), 256, 0, stream>>>(qkvb, Kpack, Vpack, band, yb);
  gemm_kernel<2><<<dim3(8, 64), 256, 0, stream>>>(yb, Wt_o, b_o, x, x2, 8192, 1024, 1024);
  ln_kernel<<<8192, 256, 0, stream>>>(x2, ln2_g, ln2_b, xn);
  gemm256_kernel<1><<<dim3(16, 32), 512, 0, stream>>>(xn, Wt_fc, b_fc, hb, 8192, 4096, 1024);
  gemm_kernel<2><<<dim3(8, 64), 256, 0, stream>>>(hb, Wt_pr, b_proj, x2, out, 8192, 1024, 4096);
}

// Round 6
// 591.782 us; speedup vs baseline: 1.2096x; 1.0144x over previous
//
#include <hip/hip_runtime.h>
#include <hip/hip_bf16.h>
#include <math.h>

// Problem constants
#define BB 8
#define LL 1024
#define DD 1024
#define FF 4096
#define NHH 8
#define HSS 128
#define SCALE 0.08838834764831845f  // 1/sqrt(128)
#define TRI(qi, kt) ((qi) * ((qi) + 1) / 2 + (kt))

typedef __bf16 bf16;
typedef __bf16 bf16x8 __attribute__((ext_vector_type(8)));
typedef float f32x4 __attribute__((ext_vector_type(4)));
typedef _Float16 f16;
typedef _Float16 f16x4 __attribute__((ext_vector_type(4)));

__device__ inline void async_copy16(const void* g, void* l) {
  __builtin_amdgcn_global_load_lds(
      (const __attribute__((address_space(1))) unsigned int*)g,
      (__attribute__((address_space(3))) unsigned int*)l, 16, 0, 0);
}

#define FENCE() asm volatile("" ::: "memory")
#define BARRIER() do { FENCE(); __builtin_amdgcn_s_barrier(); FENCE(); } while (0)
#define VMCNT0() asm volatile("s_waitcnt vmcnt(0)" ::: "memory")
#define VMCNT2() asm volatile("s_waitcnt vmcnt(2)" ::: "memory")
#define VMCNT4() asm volatile("s_waitcnt vmcnt(4)" ::: "memory")
#define VMCNT6() asm volatile("s_waitcnt vmcnt(6)" ::: "memory")

// ---------------------------------------------------------------------------
// Transpose + cast: W [K][N] fp32 -> Wt [N][K] bf16
// ---------------------------------------------------------------------------
__global__ __launch_bounds__(256)
void transpose_cast_kernel(const float* __restrict__ W, bf16* __restrict__ Wt,
                           int K, int N) {
  __shared__ float tile[32][33];
  int n0 = blockIdx.x * 32, k0 = blockIdx.y * 32;
  int tx = threadIdx.x, ty = threadIdx.y;
#pragma unroll
  for (int i = 0; i < 32; i += 8)
    tile[ty + i][tx] = W[(size_t)(k0 + ty + i) * N + n0 + tx];
  __syncthreads();
#pragma unroll
  for (int i = 0; i < 32; i += 8)
    Wt[(size_t)(n0 + ty + i) * K + k0 + tx] = (bf16)tile[tx][ty + i];
}

// ---------------------------------------------------------------------------
// pack_er: Er [1024][128] fp32 -> ErP fragment-major bf16.
// ---------------------------------------------------------------------------
__global__ __launch_bounds__(256)
void pack_er_kernel(const float* __restrict__ Er, bf16* __restrict__ ErP) {
  int g = blockIdx.x, tid = threadIdx.x;
  int l15 = tid & 15, quad = (tid >> 4) & 3, st = tid >> 6;
  const float* src = Er + (size_t)(g * 16 + l15) * HSS + st * 32 + quad * 8;
  bf16* dst = ErP + (size_t)g * 2048 + tid * 8;
#pragma unroll
  for (int j = 0; j < 8; j++) dst[j] = (bf16)src[j];
}

// ---------------------------------------------------------------------------
// LayerNorm: x [8192][1024] fp32 -> out bf16
// ---------------------------------------------------------------------------
__global__ __launch_bounds__(256)
void ln_kernel(const float* __restrict__ x, const float* __restrict__ g,
               const float* __restrict__ bta, bf16* __restrict__ out) {
  int row = blockIdx.x;
  int tid = threadIdx.x;
  const float4 v = ((const float4*)(x + (size_t)row * DD))[tid];
  float s = v.x + v.y + v.z + v.w;
  float s2 = v.x * v.x + v.y * v.y + v.z * v.z + v.w * v.w;
#pragma unroll
  for (int o = 32; o > 0; o >>= 1) {
    s += __shfl_down(s, o);
    s2 += __shfl_down(s2, o);
  }
  __shared__ float a1[4], a2[4];
  int wave = tid >> 6;
  if ((tid & 63) == 0) { a1[wave] = s; a2[wave] = s2; }
  __syncthreads();
  s = a1[0] + a1[1] + a1[2] + a1[3];
  s2 = a2[0] + a2[1] + a2[2] + a2[3];
  float mu = s * (1.0f / DD);
  float rstd = rsqrtf(s2 * (1.0f / DD) - mu * mu + 1e-5f);
  float4 gv = ((const float4*)g)[tid];
  float4 bv = ((const float4*)bta)[tid];
  bf16* o4 = out + (size_t)row * DD + tid * 4;
  o4[0] = (bf16)((v.x - mu) * rstd * gv.x + bv.x);
  o4[1] = (bf16)((v.y - mu) * rstd * gv.y + bv.y);
  o4[2] = (bf16)((v.z - mu) * rstd * gv.z + bv.z);
  o4[3] = (bf16)((v.w - mu) * rstd * gv.w + bv.w);
}

// ---------------------------------------------------------------------------
// GEMM 256x256 8-phase (FC): A-lite rev.
//  - Both B quadrants held in regs from ph0 (ph1/ph3 have no ds_reads;
//    24 ds_read_b128/K-tile, better lgkm pipelining).
//  - K-loop unrolled x2 so buffer index is compile-time (address hoisting).
//  - Ledger: B1(t) read moved to ph0; covering wait = t-1 ph3 vmcnt(6)
//    (completes B1(t),B0(t)) which precedes t ph0. All other waits as R5
//    (verified passing).
// nk must be EVEN (K=1024 -> 16).
// ---------------------------------------------------------------------------
template <int EPI>
__global__ __launch_bounds__(512)
void gemm256_kernel(const bf16* __restrict__ A, const bf16* __restrict__ Bt,
                    const float* __restrict__ bias, void* __restrict__ Cout,
                    int M, int N, int K) {
  __shared__ bf16 Als[2][256 * 64];
  __shared__ bf16 Bls[2][256 * 64];
  int tid = threadIdx.x;
  int wave = tid >> 6, lane = tid & 63;
  int l15 = lane & 15, quad = lane >> 4;
  int wmi = wave >> 2, wni = wave & 3;
  int m0 = blockIdx.y * 256, n0 = blockIdx.x * 256;

  int u0 = tid, u1 = tid + 512;
  int r0 = u0 >> 3, c0 = ((u0 & 7) ^ (r0 & 7)) << 3;
  int r1 = u1 >> 3, c1 = ((u1 & 7) ^ (r1 & 7)) << 3;
  const bf16* aB0 = A + (size_t)(m0 + r0) * K + c0;
  const bf16* aB1 = A + (size_t)(m0 + r1) * K + c1;
  const bf16* bB0 = Bt + (size_t)(n0 + r0) * K + c0;
  const bf16* bB1 = Bt + (size_t)(n0 + r1) * K + c1;
  int d0 = u0 * 8, d1 = u1 * 8;

  auto stageA = [&](int b, int h, int t) {
    size_t off = (size_t)h * 128 * K + (size_t)t * 64;
    async_copy16(aB0 + off, &Als[b][h * 8192 + d0]);
    async_copy16(aB1 + off, &Als[b][h * 8192 + d1]);
  };
  auto stageB = [&](int b, int h, int t) {
    size_t off = (size_t)h * 128 * K + (size_t)t * 64;
    async_copy16(bB0 + off, &Bls[b][h * 8192 + d0]);
    async_copy16(bB1 + off, &Bls[b][h * 8192 + d1]);
  };

  f32x4 acc[8][4] = {};
  bf16x8 af[2][4], bfr[2][2][2];  // bfr[qn][kk][nt]

  auto readA = [&](int b, int qm) {
#pragma unroll
    for (int kk = 0; kk < 2; kk++)
#pragma unroll
      for (int mt = 0; mt < 4; mt++) {
        int ra = qm * 128 + wmi * 64 + mt * 16 + l15;
        af[kk][mt] = *(const bf16x8*)&Als[b][ra * 64 + (((kk * 4 + quad) ^ (ra & 7)) << 3)];
      }
  };
  auto readB = [&](int b, int qn) {
#pragma unroll
    for (int kk = 0; kk < 2; kk++)
#pragma unroll
      for (int nt = 0; nt < 2; nt++) {
        int rb = qn * 128 + wni * 32 + nt * 16 + l15;
        bfr[qn][kk][nt] = *(const bf16x8*)&Bls[b][rb * 64 + (((kk * 4 + quad) ^ (rb & 7)) << 3)];
      }
  };
  auto mfma16 = [&](int qm, int qn) {
    __builtin_amdgcn_s_setprio(1);
#pragma unroll
    for (int kk = 0; kk < 2; kk++)
#pragma unroll
      for (int mt = 0; mt < 4; mt++)
#pragma unroll
        for (int nt = 0; nt < 2; nt++)
          acc[qm * 4 + mt][qn * 2 + nt] = __builtin_amdgcn_mfma_f32_16x16x32_bf16(
              af[kk][mt], bfr[qn][kk][nt], acc[qm * 4 + mt][qn * 2 + nt], 0, 0, 0);
    __builtin_amdgcn_s_setprio(0);
  };

  int nk = K >> 6;  // even
  // prologue: A0(0) B0(0) B1(0) A1(0) A0(1) B1(1); wait oldest 3 stages.
  stageA(0, 0, 0); stageB(0, 0, 0); stageB(0, 1, 0); stageA(0, 1, 0);
  stageA(1, 0, 1); stageB(1, 1, 1);
  VMCNT6();
  BARRIER();

  for (int t = 0; t < nk; t += 2) {
#pragma unroll
    for (int uu = 0; uu < 2; uu++) {
      const int tt = t + uu;
      const int cur = uu;  // tt & 1 (t even) -> compile-time
      // ph0: quadrant (0,0); read A0 + BOTH B quadrants
      readA(cur, 0); readB(cur, 0); readB(cur, 1);
      if (tt + 1 < nk) stageB(cur ^ 1, 0, tt + 1);
      BARRIER();
      mfma16(0, 0);
      BARRIER();
      // ph1: quadrant (0,1)
      if (tt + 1 < nk) stageA(cur ^ 1, 1, tt + 1);
      VMCNT6();
      BARRIER();
      mfma16(0, 1);
      BARRIER();
      // ph2: quadrant (1,1)
      readA(cur, 1);
      if (tt + 2 < nk) stageA(cur, 0, tt + 2);
      BARRIER();
      mfma16(1, 1);
      BARRIER();
      // ph3: quadrant (1,0)
      if (tt + 2 < nk) stageB(cur, 1, tt + 2);
      VMCNT6();
      BARRIER();
      mfma16(1, 0);
      BARRIER();
    }
  }

#pragma unroll
  for (int MT = 0; MT < 8; MT++) {
#pragma unroll
    for (int NT = 0; NT < 4; NT++) {
      int col = n0 + (NT >> 1) * 128 + wni * 32 + (NT & 1) * 16 + l15;
      float bv = bias[col];
#pragma unroll
      for (int r = 0; r < 4; r++) {
        int row = m0 + (MT >> 2) * 128 + wmi * 64 + (MT & 3) * 16 + quad * 4 + r;
        float v = acc[MT][NT][r] + bv;
        if (EPI == 1) v = 0.5f * v * (1.0f + erff(v * 0.7071067811865475f));
        ((bf16*)Cout)[(size_t)row * N + col] = (bf16)v;
      }
    }
  }
}

// ---------------------------------------------------------------------------
// GEMM 256x128 2-phase (QKV/proj): C = A[M][K] * Bt[N][K]^T + bias (+res).
// Grid (N/128, M/256). 8 waves (2M x 4N), wave out 128x32, BK=64.
// LDS 96KB: A dbuf 2x32KB + B dbuf 2x16KB. B staged 2 tiles deep (B(t) in
// Bls[t&1]); A 1 deep. Per K-tile: ph0 {readA0+readB(12), stage A0(t+1),
// vmcnt4, bar, mfma, bar}, ph1 {readA1(8), stage A1(t+1)+B(t+2), vmcnt4,
// bar, mfma, bar}. Ledger (verified incl. tail): steady-state ph1 vmcnt(4)
// with 8 outstanding completes B(t+2-?)..: each read covered by a wait >=1
// phase earlier; tail: ph0 else VMCNT0 (last tile only), ph1 else VMCNT2.
// EPI 0: -> bf16   EPI 2: + res(fp32) -> fp32
// ---------------------------------------------------------------------------
template <int EPI>
__global__ __launch_bounds__(512)
void gemm256n_kernel(const bf16* __restrict__ A, const bf16* __restrict__ Bt,
                     const float* __restrict__ bias, const float* __restrict__ res,
                     void* __restrict__ Cout, int M, int N, int K) {
  __shared__ bf16 Als[2][256 * 64];
  __shared__ bf16 Bls[2][128 * 64];
  int tid = threadIdx.x;
  int wave = tid >> 6, lane = tid & 63;
  int l15 = lane & 15, quad = lane >> 4;
  int wmi = wave >> 2, wni = wave & 3;
  int m0 = blockIdx.y * 256, n0 = blockIdx.x * 128;

  int u0 = tid, u1 = tid + 512;
  int r0 = u0 >> 3, c0 = ((u0 & 7) ^ (r0 & 7)) << 3;
  int r1 = u1 >> 3, c1 = ((u1 & 7) ^ (r1 & 7)) << 3;
  const bf16* aB0 = A + (size_t)(m0 + r0) * K + c0;
  const bf16* aB1 = A + (size_t)(m0 + r1) * K + c1;
  const bf16* bB0 = Bt + (size_t)(n0 + r0) * K + c0;
  const bf16* bB1 = Bt + (size_t)(n0 + r1) * K + c1;
  int d0 = u0 * 8, d1 = u1 * 8;

  auto stageA = [&](int b, int h, int t) {
    size_t off = (size_t)h * 128 * K + (size_t)t * 64;
    async_copy16(aB0 + off, &Als[b][h * 8192 + d0]);
    async_copy16(aB1 + off, &Als[b][h * 8192 + d1]);
  };
  auto stageB = [&](int b, int t) {
    size_t off = (size_t)t * 64;
    async_copy16(bB0 + off, &Bls[b][d0]);
    async_copy16(bB1 + off, &Bls[b][d1]);
  };

  f32x4 acc[8][2] = {};
  bf16x8 af[2][4], bfr[2][2];

  auto readA = [&](int b, int qm) {
#pragma unroll
    for (int kk = 0; kk < 2; kk++)
#pragma unroll
      for (int mt = 0; mt < 4; mt++) {
        int ra = qm * 128 + wmi * 64 + mt * 16 + l15;
        af[kk][mt] = *(const bf16x8*)&Als[b][ra * 64 + (((kk * 4 + quad) ^ (ra & 7)) << 3)];
      }
  };
  auto readB = [&](int b) {
#pragma unroll
    for (int kk = 0; kk < 2; kk++)
#pragma unroll
      for (int nt = 0; nt < 2; nt++) {
        int rb = wni * 32 + nt * 16 + l15;
        bfr[kk][nt] = *(const bf16x8*)&Bls[b][rb * 64 + (((kk * 4 + quad) ^ (rb & 7)) << 3)];
      }
  };
  auto mfma16 = [&](int qm) {
    __builtin_amdgcn_s_setprio(1);
#pragma unroll
    for (int kk = 0; kk < 2; kk++)
#pragma unroll
      for (int mt = 0; mt < 4; mt++)
#pragma unroll
        for (int nt = 0; nt < 2; nt++)
          acc[qm * 4 + mt][nt] = __builtin_amdgcn_mfma_f32_16x16x32_bf16(
              af[kk][mt], bfr[kk][nt], acc[qm * 4 + mt][nt], 0, 0, 0);
    __builtin_amdgcn_s_setprio(0);
  };

  int nk = K >> 6;  // even
  // prologue: B(0)->Bls[0], B(1)->Bls[1], A0(0), A1(0); drain (one-time).
  stageB(0, 0); stageB(1, 1); stageA(0, 0, 0); stageA(0, 1, 0);
  VMCNT0();
  BARRIER();

  for (int t = 0; t < nk; t += 2) {
#pragma unroll
    for (int uu = 0; uu < 2; uu++) {
      const int tt = t + uu;
      const int cur = uu;
      // ph0
      readA(cur, 0); readB(cur);
      if (tt + 1 < nk) { stageA(cur ^ 1, 0, tt + 1); VMCNT4(); }
      else { VMCNT0(); }  // last tile only
      BARRIER();
      mfma16(0);
      BARRIER();
      // ph1
      readA(cur, 1);
      if (tt + 1 < nk) stageA(cur ^ 1, 1, tt + 1);
      if (tt + 2 < nk) { stageB(cur, tt + 2); VMCNT4(); }
      else { VMCNT2(); }
      BARRIER();
      mfma16(1);
      BARRIER();
    }
  }

#pragma unroll
  for (int MT = 0; MT < 8; MT++) {
#pragma unroll
    for (int NT = 0; NT < 2; NT++) {
      int col = n0 + wni * 32 + NT * 16 + l15;
      float bv = bias[col];
#pragma unroll
      for (int r = 0; r < 4; r++) {
        int row = m0 + (MT >> 2) * 128 + wmi * 64 + (MT & 3) * 16 + quad * 4 + r;
        float v = acc[MT][NT][r] + bv;
        if (EPI == 2) {
          v += res[(size_t)row * N + col];
          ((float*)Cout)[(size_t)row * N + col] = v;
        } else {
          ((bf16*)Cout)[(size_t)row * N + col] = (bf16)v;
        }
      }
    }
  }
}

// ---------------------------------------------------------------------------
// GEMM v3 (m97 structure), kept for attn-out (N=1024, K=1024, EPI 2).
// ---------------------------------------------------------------------------
template <int EPI>
__global__ __launch_bounds__(256)
void gemm_kernel(const bf16* __restrict__ A, const bf16* __restrict__ Bt,
                 const float* __restrict__ bias, const float* __restrict__ res,
                 void* __restrict__ Cout, int M, int N, int K) {
  __shared__ bf16 Als[128 * 64];
  __shared__ bf16 Bls[128 * 64];
  int tid = threadIdx.x;
  int wave = tid >> 6, lane = tid & 63;
  int l15 = lane & 15, quad = lane >> 4;

  int m0 = blockIdx.y * 128, n0 = blockIdx.x * 128;
  int wm = (wave >> 1) * 64, wn = (wave & 1) * 64;
  f32x4 acc[4][4] = {};

  const bf16* asrc[4];
  const bf16* bsrc[4];
  int ldso[4];
#pragma unroll
  for (int i = 0; i < 4; i++) {
    int u = i * 256 + tid;
    int row = u >> 3, c = u & 7;
    int g = c ^ (row & 7);
    asrc[i] = A + (size_t)(m0 + row) * K + g * 8;
    bsrc[i] = Bt + (size_t)(n0 + row) * K + g * 8;
    ldso[i] = u * 8;
  }

  for (int k0 = 0; k0 < K; k0 += 64) {
    __syncthreads();
#pragma unroll
    for (int i = 0; i < 4; i++) {
      async_copy16(asrc[i] + k0, &Als[ldso[i]]);
      async_copy16(bsrc[i] + k0, &Bls[ldso[i]]);
    }
    __syncthreads();

    bf16x8 af[2][4], bfr[2][4];
#pragma unroll
    for (int kk = 0; kk < 2; kk++) {
#pragma unroll
      for (int mt = 0; mt < 4; mt++) {
        int ra = wm + mt * 16 + l15;
        af[kk][mt] = *(const bf16x8*)&Als[ra * 64 + (((kk * 4 + quad) ^ (ra & 7)) << 3)];
        int rb = wn + mt * 16 + l15;
        bfr[kk][mt] = *(const bf16x8*)&Bls[rb * 64 + (((kk * 4 + quad) ^ (rb & 7)) << 3)];
      }
    }
#pragma unroll
    for (int kk = 0; kk < 2; kk++)
#pragma unroll
      for (int mt = 0; mt < 4; mt++)
#pragma unroll
        for (int nt = 0; nt < 4; nt++)
          acc[mt][nt] = __builtin_amdgcn_mfma_f32_16x16x32_bf16(af[kk][mt], bfr[kk][nt],
                                                                acc[mt][nt], 0, 0, 0);
  }

#pragma unroll
  for (int mt = 0; mt < 4; mt++) {
#pragma unroll
    for (int nt = 0; nt < 4; nt++) {
      int col = n0 + wn + nt * 16 + l15;
      float bv = bias[col];
#pragma unroll
      for (int r = 0; r < 4; r++) {
        int row = m0 + wm + mt * 16 + quad * 4 + r;
        float v = acc[mt][nt][r] + bv;
        if (EPI == 1) v = 0.5f * v * (1.0f + erff(v * 0.7071067811865475f));
        if (EPI == 2) {
          v += res[(size_t)row * N + col];
          ((float*)Cout)[(size_t)row * N + col] = v;
        } else {
          ((bf16*)Cout)[(size_t)row * N + col] = (bf16)v;
        }
      }
    }
  }
}

// ---------------------------------------------------------------------------
// pack_kv: per (b,h,kt) repack K into [kk][chunk^swizzle] and V transposed
// into [d][chunk^swizzle], 16B chunks.
// ---------------------------------------------------------------------------
__global__ __launch_bounds__(256)
void pack_kv_kernel(const bf16* __restrict__ qkv, bf16* __restrict__ Kpack,
                    bf16* __restrict__ Vpack) {
  __shared__ bf16 Vst[64][132];
  int kt = blockIdx.x, h = blockIdx.y, b = blockIdx.z;
  int tid = threadIdx.x;
  const size_t rs = 3 * DD;
  const bf16* kb = qkv + (size_t)b * LL * rs + (size_t)(kt * 64) * rs + DD + h * HSS;
  const bf16* vb = kb + DD;
  bf16* kp = Kpack + ((size_t)(b * NHH + h) * 16 + kt) * (64 * 128);
  bf16* vp = Vpack + ((size_t)(b * NHH + h) * 16 + kt) * (128 * 64);
#pragma unroll
  for (int i = 0; i < 4; i++) {
    int u = i * 256 + tid;
    int kk = u >> 4, c = u & 15;
    bf16x8 kv = *(const bf16x8*)(kb + (size_t)kk * rs + c * 8);
    *(bf16x8*)(kp + kk * 128 + ((c ^ kk) & 15) * 8) = kv;
    *(bf16x8*)&Vst[kk][c * 8] = *(const bf16x8*)(vb + (size_t)kk * rs + c * 8);
  }
  __syncthreads();
#pragma unroll
  for (int i = 0; i < 4; i++) {
    int u = i * 256 + tid;
    int d = u >> 3, c = u & 7;
    bf16x8 t;
#pragma unroll
    for (int j = 0; j < 8; j++) t[j] = Vst[c * 8 + j][d];
    *(bf16x8*)(vp + d * 64 + ((c ^ (d & 7))) * 8) = t;
  }
}

// ---------------------------------------------------------------------------
// relband v4: paired q-tiles, fragment-major ErP loads, Q loaded once/q-tile.
// ---------------------------------------------------------------------------
__global__ __launch_bounds__(256)
void relband_kernel(const bf16* __restrict__ qkv, const bf16* __restrict__ ErP,
                    f16* __restrict__ band) {
  int tid = threadIdx.x, wave = tid >> 6, lane = tid & 63;
  int l15 = lane & 15, quad = lane >> 4;
  int h = blockIdx.y, b = blockIdx.z;
  const size_t rs = 3 * DD;
  const bf16* qbase = qkv + (size_t)b * LL * rs + h * HSS;
  f16* bbase = band + (size_t)(b * NHH + h) * (136 * 4096);

#pragma unroll 1
  for (int ph = 0; ph < 2; ph++) {
    int qb = ph ? 15 - blockIdx.x : blockIdx.x;
    int qw0 = qb * 64 + wave * 16;

    bf16x8 qf[4];
#pragma unroll
    for (int st = 0; st < 4; st++)
      qf[st] = *(const bf16x8*)(qbase + (size_t)(qw0 + l15) * rs + st * 32 + quad * 8);

#pragma unroll 1
    for (int kt = 0; kt <= qb; kt++) {
      int k0 = kt * 64;
      int kmax_off = qw0 + 15 - k0;
      int m_base = 1008 - qw0 + k0;
      int gb = m_base >> 4;
      int ntR = (kmax_off >> 4) + 1;
      if (ntR > 4) ntR = 4;

      f32x4 rr[5] = {};
#pragma unroll
      for (int n = 0; n < 5; n++) {
        if (n <= ntR) {
          int g = gb + n;
          if (g > 63) g = 63;
          const bf16* ep = ErP + (size_t)g * 2048 + lane * 8;
#pragma unroll
          for (int st = 0; st < 4; st++) {
            bf16x8 ef = *(const bf16x8*)(ep + st * 512);
            rr[n] = __builtin_amdgcn_mfma_f32_16x16x32_bf16(qf[st], ef, rr[n], 0, 0, 0);
          }
        }
      }

      f16x4 sf[4];
#pragma unroll
      for (int rg = 0; rg < 4; rg++) {
        int qloc = quad * 4 + rg;
        int tt = 15 - qloc + l15;
        int src = (lane & 48) | (tt & 15);
        float shv[5];
#pragma unroll
        for (int n = 0; n < 5; n++)
          shv[n] = (n <= ntR) ? __shfl(rr[n][rg], src) : 0.f;
#pragma unroll
        for (int nt = 0; nt < 4; nt++)
          sf[nt][rg] = (f16)((tt & 16) ? shv[nt + 1] : shv[nt]);
      }
      f16* tb = bbase + (size_t)TRI(qb, kt) * 4096;
#pragma unroll
      for (int nt = 0; nt < 4; nt++)
        if (nt * 16 <= kmax_off)
          *(f16x4*)(tb + (wave * 4 + nt) * 256 + l15 * 16 + quad * 4) = sf[nt];
    }
  }
}

// ---------------------------------------------------------------------------
// Flash attention v6 (R2-proven): balanced pairing + LDS double-buffered K/V
// DMA.
// ---------------------------------------------------------------------------
__global__ __launch_bounds__(256)
void flash_kernel(const bf16* __restrict__ qkv, const bf16* __restrict__ Kpack,
                  const bf16* __restrict__ Vpack, const f16* __restrict__ band,
                  bf16* __restrict__ y) {
  __shared__ bf16 Kls[2][64 * 128];
  __shared__ bf16 Vls[2][128 * 64];
  __shared__ bf16 Pls[4][16][72];

  int tid = threadIdx.x, wave = tid >> 6, lane = tid & 63;
  int l15 = lane & 15, quad = lane >> 4;
  int h = blockIdx.y, b = blockIdx.z;

  const size_t rs = 3 * DD;
  const bf16* qbase = qkv + (size_t)b * LL * rs + h * HSS;
  const bf16* kp = Kpack + (size_t)(b * NHH + h) * 16 * (64 * 128);
  const bf16* vp = Vpack + (size_t)(b * NHH + h) * 16 * (128 * 64);
  const f16* bnd = band + (size_t)(b * NHH + h) * (136 * 4096);

  int buf = 0;
#pragma unroll 1
  for (int ph = 0; ph < 2; ph++) {
    int qb = ph ? 15 - blockIdx.x : blockIdx.x;
    int qw0 = qb * 64 + wave * 16;
    int nkt = qb + 1;

    bf16x8 qf[4];
#pragma unroll
    for (int st = 0; st < 4; st++)
      qf[st] = *(const bf16x8*)(qbase + (size_t)(qw0 + l15) * rs + st * 32 + quad * 8);

    {
      const bf16* ks = kp;
      const bf16* vs = vp;
#pragma unroll
      for (int i = 0; i < 4; i++) {
        int off = (wave * 4 + i) * 512 + lane * 8;
        async_copy16(ks + off, &Kls[buf][off]);
        async_copy16(vs + off, &Vls[buf][off]);
      }
    }

    f32x4 o[8] = {};
    float mrow[4] = {-INFINITY, -INFINITY, -INFINITY, -INFINITY};
    float lrow[4] = {0.f, 0.f, 0.f, 0.f};

#pragma unroll 1
    for (int kt = 0; kt < nkt; kt++) {
      int k0 = kt * 64;
      int kmax_off = qw0 + 15 - k0;
      __syncthreads();

      const f16* tb = bnd + (size_t)TRI(qb, kt) * 4096;
      f16x4 srl[4] = {};
#pragma unroll
      for (int nt = 0; nt < 4; nt++)
        if (nt * 16 <= kmax_off)
          srl[nt] = *(const f16x4*)(tb + (wave * 4 + nt) * 256 + l15 * 16 + quad * 4);

      if (kt + 1 < nkt) {
        const bf16* ks = kp + (size_t)(kt + 1) * (64 * 128);
        const bf16* vs = vp + (size_t)(kt + 1) * (128 * 64);
#pragma unroll
        for (int i = 0; i < 4; i++) {
          int off = (wave * 4 + i) * 512 + lane * 8;
          async_copy16(ks + off, &Kls[buf ^ 1][off]);
          async_copy16(vs + off, &Vls[buf ^ 1][off]);
        }
      }

      f32x4 sa[4] = {};
#pragma unroll
      for (int nt = 0; nt < 4; nt++) {
        if (nt * 16 <= kmax_off) {
          int kk = nt * 16 + l15;
#pragma unroll
          for (int st = 0; st < 4; st++) {
            bf16x8 kf = *(const bf16x8*)&Kls[buf][kk * 128 + (((st * 4 + quad) ^ l15) & 15) * 8];
            sa[nt] = __builtin_amdgcn_mfma_f32_16x16x32_bf16(qf[st], kf, sa[nt], 0, 0, 0);
          }
        }
      }

      float pmx[4] = {-INFINITY, -INFINITY, -INFINITY, -INFINITY};
#pragma unroll
      for (int nt = 0; nt < 4; nt++) {
        if (nt * 16 <= kmax_off) {
          int kg = k0 + nt * 16 + l15;
#pragma unroll
          for (int rg = 0; rg < 4; rg++) {
            int qg = qw0 + quad * 4 + rg;
            float v = (sa[nt][rg] + (float)srl[nt][rg]) * SCALE;
            v = (kg <= qg) ? v : -INFINITY;
            sa[nt][rg] = v;
            pmx[rg] = fmaxf(pmx[rg], v);
          }
        } else {
#pragma unroll
          for (int rg = 0; rg < 4; rg++) sa[nt][rg] = -INFINITY;
        }
      }

#pragma unroll
      for (int rg = 0; rg < 4; rg++) {
        float v = pmx[rg];
        v = fmaxf(v, __shfl_xor(v, 1));
        v = fmaxf(v, __shfl_xor(v, 2));
        v = fmaxf(v, __shfl_xor(v, 4));
        v = fmaxf(v, __shfl_xor(v, 8));
        float mnew = fmaxf(mrow[rg], v);
        float alpha = __expf(mrow[rg] - mnew);
        mrow[rg] = mnew;
        lrow[rg] *= alpha;
#pragma unroll
        for (int nt = 0; nt < 8; nt++) o[nt][rg] *= alpha;
        pmx[rg] = mnew;
      }
      float ls[4] = {0.f, 0.f, 0.f, 0.f};
#pragma unroll
      for (int nt = 0; nt < 4; nt++)
#pragma unroll
        for (int rg = 0; rg < 4; rg++) {
          float p = __expf(sa[nt][rg] - pmx[rg]);
          ls[rg] += p;
          Pls[wave][quad * 4 + rg][nt * 16 + l15] = (bf16)p;
        }
#pragma unroll
      for (int rg = 0; rg < 4; rg++) {
        float v = ls[rg];
        v += __shfl_xor(v, 1);
        v += __shfl_xor(v, 2);
        v += __shfl_xor(v, 4);
        v += __shfl_xor(v, 8);
        lrow[rg] += v;
      }

      bf16x8 pf[2];
#pragma unroll
      for (int s2 = 0; s2 < 2; s2++)
        pf[s2] = *(const bf16x8*)&Pls[wave][l15][s2 * 32 + quad * 8];
#pragma unroll
      for (int nt = 0; nt < 8; nt++) {
        int d = nt * 16 + l15;
#pragma unroll
        for (int s2 = 0; s2 < 2; s2++) {
          if (s2 * 32 <= kmax_off) {
            bf16x8 vf = *(const bf16x8*)&Vls[buf][d * 64 + (((s2 * 4 + quad) ^ (l15 & 7)) & 7) * 8];
            o[nt] = __builtin_amdgcn_mfma_f32_16x16x32_bf16(pf[s2], vf, o[nt], 0, 0, 0);
          }
        }
      }
      buf ^= 1;
    }

#pragma unroll
    for (int rg = 0; rg < 4; rg++) {
      float inv = 1.0f / lrow[rg];
      int qg = qw0 + quad * 4 + rg;
      bf16* yr = y + ((size_t)b * LL + qg) * DD + h * HSS;
#pragma unroll
      for (int nt = 0; nt < 8; nt++) yr[nt * 16 + l15] = (bf16)(o[nt][rg] * inv);
    }
  }
}

// ---------------------------------------------------------------------------
extern "C" void kernel_launch(void* const* d_in, const int* in_sizes, int n_in,
                              void* d_out, int out_size, void* d_ws, size_t ws_size,
                              hipStream_t stream) {
  const float* x = (const float*)d_in[0];
  const float* W_qkv = (const float*)d_in[1];
  const float* b_qkv = (const float*)d_in[2];
  const float* W_o = (const float*)d_in[3];
  const float* b_o = (const float*)d_in[4];
  const float* Er = (const float*)d_in[5];
  const float* ln1_g = (const float*)d_in[6];
  const float* ln1_b = (const float*)d_in[7];
  const float* ln2_g = (const float*)d_in[8];
  const float* ln2_b = (const float*)d_in[9];
  const float* W_fc = (const float*)d_in[10];
  const float* b_fc = (const float*)d_in[11];
  const float* W_proj = (const float*)d_in[12];
  const float* b_proj = (const float*)d_in[13];
  float* out = (float*)d_out;

  char* p = (char*)d_ws;
  auto alloc = [&](size_t bytes) {
    char* r = p;
    p += (bytes + 255) & ~(size_t)255;
    return r;
  };
  bf16* Wt_qkv = (bf16*)alloc((size_t)3072 * 1024 * 2);
  bf16* Wt_o   = (bf16*)alloc((size_t)1024 * 1024 * 2);
  bf16* Wt_fc  = (bf16*)alloc((size_t)4096 * 1024 * 2);
  bf16* Wt_pr  = (bf16*)alloc((size_t)1024 * 4096 * 2);
  bf16* ErP    = (bf16*)alloc((size_t)1024 * 128 * 2);
  bf16* xn     = (bf16*)alloc((size_t)8192 * 1024 * 2);
  bf16* qkvb   = (bf16*)alloc((size_t)8192 * 3072 * 2);  // + yb = hb region
  bf16* yb     = (bf16*)alloc((size_t)8192 * 1024 * 2);  // must follow qkvb
  bf16* Kpack  = (bf16*)alloc((size_t)64 * 16 * 64 * 128 * 2);
  bf16* Vpack  = (bf16*)alloc((size_t)64 * 16 * 128 * 64 * 2);
  f16*  band   = (f16*)alloc((size_t)64 * 136 * 4096 * 2);  // 71.3 MB
  float* x2    = (float*)band;  // alias: band dead before x2 is written
  bf16* hb     = qkvb;          // spans qkvb+yb (66MB >= 64MB needed)

  // weight prep
  transpose_cast_kernel<<<dim3(3072 / 32, 1024 / 32), dim3(32, 8), 0, stream>>>(W_qkv, Wt_qkv, 1024, 3072);
  transpose_cast_kernel<<<dim3(1024 / 32, 1024 / 32), dim3(32, 8), 0, stream>>>(W_o, Wt_o, 1024, 1024);
  transpose_cast_kernel<<<dim3(4096 / 32, 1024 / 32), dim3(32, 8), 0, stream>>>(W_fc, Wt_fc, 1024, 4096);
  transpose_cast_kernel<<<dim3(1024 / 32, 4096 / 32), dim3(32, 8), 0, stream>>>(W_proj, Wt_pr, 4096, 1024);
  pack_er_kernel<<<64, 256, 0, stream>>>(Er, ErP);

  // block
  ln_kernel<<<8192, 256, 0, stream>>>(x, ln1_g, ln1_b, xn);
  gemm256n_kernel<0><<<dim3(24, 32), 512, 0, stream>>>(xn, Wt_qkv, b_qkv, nullptr, qkvb, 8192, 3072, 1024);
  pack_kv_kernel<<<dim3(16, 8, 8), 256, 0, stream>>>(qkvb, Kpack, Vpack);
  relband_kernel<<<dim3(8, 8, 8), 256, 0, stream>>>(qkvb, ErP, band);
  flash_kernel<<<dim3(8, 8, 8), 256, 0, stream>>>(qkvb, Kpack, Vpack, band, yb);
  gemm_kernel<2><<<dim3(8, 64), 256, 0, stream>>>(yb, Wt_o, b_o, x, x2, 8192, 1024, 1024);
  ln_kernel<<<8192, 256, 0, stream>>>(x2, ln2_g, ln2_b, xn);
  gemm256_kernel<1><<<dim3(16, 32), 512, 0, stream>>>(xn, Wt_fc, b_fc, hb, 8192, 4096, 1024);
  gemm256n_kernel<2><<<dim3(8, 32), 512, 0, stream>>>(hb, Wt_pr, b_proj, x2, out, 8192, 1024, 4096);
}